// Round 6
// baseline (687.478 us; speedup 1.0000x reference)
//
#include <hip/hip_runtime.h>
#include <hip/hip_bf16.h>

#define NN 50000
#define NE 400000
#define NTILE 6250         // NE/64 edge tiles
#define NCH 196            // ceil(50176/256) scan chunks
#define NPAD 50176         // NCH*256

typedef __bf16 bf16_t;
typedef __bf16 bf16x8 __attribute__((ext_vector_type(8)));
typedef float  floatx4 __attribute__((ext_vector_type(4)));

static __device__ __forceinline__ floatx4 mfma16(bf16x8 a, bf16x8 b, floatx4 c) {
    return __builtin_amdgcn_mfma_f32_16x16x32_bf16(a, b, c, 0, 0, 0);
}
static __device__ __forceinline__ float sigm_f(float x) {
    return 1.f / (1.f + __expf(-x));
}
static __device__ __forceinline__ float tanh_f(float x) {
    return 1.f - 2.f / (__expf(2.f * x) + 1.f);
}
static __device__ __forceinline__ bf16x8 cvt8(const float* sp) {
    float4 f0 = *(const float4*)sp;
    float4 f1 = *(const float4*)(sp + 4);
    bf16x8 v;
    v[0] = (bf16_t)f0.x; v[1] = (bf16_t)f0.y; v[2] = (bf16_t)f0.z; v[3] = (bf16_t)f0.w;
    v[4] = (bf16_t)f1.x; v[5] = (bf16_t)f1.y; v[6] = (bf16_t)f1.z; v[7] = (bf16_t)f1.w;
    return v;
}

// ---------------------------------------------------------------------------
// prep: weights into MFMA-fragment-linear bf16 order.
// W1f[((nt*5+ks)*64+l)*8+j] = W1[k=ks*32+(l>>4)*8+j][n=nt*16+(l&15)], k<136 else 0
// W2f[((nt*4+kg)*64+l)*8+j] = W2[k=kg*32+(l>>4)*8+j][n=nt*16+(l&15)]
// Wxt/Wht: [n][k] transposed bf16 for the GRU (as R5).
// ---------------------------------------------------------------------------
__global__ __launch_bounds__(256) void prep_kernel(
    const float* __restrict__ Wm1, const float* __restrict__ Wm2,
    const float* __restrict__ Wx,  const float* __restrict__ Wh,
    bf16_t* __restrict__ W1f, bf16_t* __restrict__ W2f,
    bf16_t* __restrict__ Wxt, bf16_t* __restrict__ Wht)
{
    int u = blockIdx.x * 256 + threadIdx.x;
    if (u < 20480) {
        int j = u & 7, l = (u >> 3) & 63, rem = u >> 9;   // rem 0..39
        int ks = rem % 5, nt = rem / 5;
        int n = nt * 16 + (l & 15);
        int k = ks * 32 + (l >> 4) * 8 + j;
        W1f[u] = (k < 136) ? (bf16_t)Wm1[k * 128 + n] : (bf16_t)0.f;
        return;
    }
    u -= 20480;
    if (u < 8192) {
        int j = u & 7, l = (u >> 3) & 63, rem = u >> 9;   // rem 0..15
        int kg = rem & 3, nt = rem >> 2;
        int n = nt * 16 + (l & 15);
        int k = kg * 32 + (l >> 4) * 8 + j;
        W2f[u] = (bf16_t)Wm2[k * 64 + n];
        return;
    }
    u -= 8192;
    if (u < 12288) {
        int n = u >> 6, k = u & 63;
        Wxt[u] = (bf16_t)Wx[k * 192 + n];
        return;
    }
    u -= 12288;
    if (u < 12288) {
        int n = u >> 6, k = u & 63;
        Wht[u] = (bf16_t)Wh[k * 192 + n];
    }
}

// ---------------------------------------------------------------------------
// CSR build: hist -> scan -> scatter (permute srcs/dsts/ef, sorted by dst)
// ---------------------------------------------------------------------------
__global__ __launch_bounds__(256) void hist_kernel(
    const int* __restrict__ edst, int* __restrict__ deg)
{
    int e = blockIdx.x * 256 + threadIdx.x;
    if (e < NE) atomicAdd(&deg[edst[e]], 1);
}

__global__ __launch_bounds__(256) void scanA_kernel(
    const int* __restrict__ deg, int* __restrict__ chunkSums)
{
    __shared__ int s[256];
    int i = blockIdx.x * 256 + threadIdx.x;
    s[threadIdx.x] = deg[i];
    __syncthreads();
    for (int st = 128; st >= 1; st >>= 1) {
        if (threadIdx.x < st) s[threadIdx.x] += s[threadIdx.x + st];
        __syncthreads();
    }
    if (threadIdx.x == 0) chunkSums[blockIdx.x] = s[0];
}

__global__ __launch_bounds__(256) void scanB_kernel(
    const int* __restrict__ chunkSums, int* __restrict__ chunkOff)
{
    __shared__ int s[256];
    int t = threadIdx.x;
    int v = (t < NCH) ? chunkSums[t] : 0;
    s[t] = v;
    __syncthreads();
    for (int st = 1; st < 256; st <<= 1) {
        int add = (t >= st) ? s[t - st] : 0;
        __syncthreads();
        s[t] += add;
        __syncthreads();
    }
    if (t < NCH) chunkOff[t] = s[t] - v;   // exclusive
}

__global__ __launch_bounds__(256) void scanC_kernel(
    const int* __restrict__ deg, const int* __restrict__ chunkOff,
    int* __restrict__ cursor)
{
    __shared__ int s[256];
    int t = threadIdx.x;
    int i = blockIdx.x * 256 + t;
    int v = deg[i];
    s[t] = v;
    __syncthreads();
    for (int st = 1; st < 256; st <<= 1) {
        int add = (t >= st) ? s[t - st] : 0;
        __syncthreads();
        s[t] += add;
        __syncthreads();
    }
    cursor[i] = chunkOff[blockIdx.x] + s[t] - v;   // exclusive
}

__global__ __launch_bounds__(256) void scatter_kernel(
    const int* __restrict__ esrc, const int* __restrict__ edst,
    const float* __restrict__ ef,
    int* __restrict__ cursor, int* __restrict__ srcs, int* __restrict__ dsts,
    float* __restrict__ efp)
{
    int e = blockIdx.x * 256 + threadIdx.x;
    if (e >= NE) return;
    int d = edst[e];
    int p = atomicAdd(&cursor[d], 1);    // cursor ends at row-end offsets
    srcs[p] = esrc[e];
    dsts[p] = d;
    float4 a = *(const float4*)(ef + (size_t)e * 8);
    float4 b = *(const float4*)(ef + (size_t)e * 8 + 4);
    *(float4*)(efp + (size_t)p * 8)     = a;
    *(float4*)(efp + (size_t)p * 8 + 4) = b;
}

// ---------------------------------------------------------------------------
// edge kernel v5: persistent blocks, 64 sorted edges/tile, 16/wave.
// W1 in frag-linear LDS (lane-linear 16B reads -> 2 lanes/bank = free).
// W2 frags + biases in registers. GEMM1/GEMM2 processed in two 64-col
// halves (hs = 16x72 bf16 per wave -> LDS 49KB total -> 3 blocks/CU).
// MODE 0: plain coalesced stores of m[e][64] (no atomics -> no vmcnt
// serialization of the next tile's gather). MODE 1: atomic fallback.
// ---------------------------------------------------------------------------
template<int MODE>
__global__ __launch_bounds__(256, 3) void edge_kernel(
    const float* __restrict__ h, const float* __restrict__ efp,
    const int* __restrict__ srcs, const int* __restrict__ dsts,
    const bf16_t* __restrict__ W1f, const bf16_t* __restrict__ W2f,
    const float* __restrict__ b1f, const float* __restrict__ b2f,
    float* __restrict__ mbuf, float* __restrict__ agg)
{
    __shared__ __attribute__((aligned(16))) bf16_t w1s[20480];    // 40960 B
    __shared__ __attribute__((aligned(16))) bf16_t hs[4][16 * 72]; // 9216 B

    const int tid = threadIdx.x;

    // stage W1 frag-linear (straight memcpy, coalesced)
    {
        const uint4* s1 = (const uint4*)W1f;
        uint4* d1 = (uint4*)w1s;
        #pragma unroll
        for (int i = 0; i < 10; i++) d1[tid + i * 256] = s1[tid + i * 256];
    }
    __syncthreads();

    const int lane = tid & 63;
    const int wv   = tid >> 6;
    const int l15  = lane & 15;
    const int quad = lane >> 4;

    // W2 fragments in registers: 16 x bf16x8 (coalesced frag-linear loads)
    bf16x8 w2f[4][4];
    #pragma unroll
    for (int nt = 0; nt < 4; nt++)
        #pragma unroll
        for (int kg = 0; kg < 4; kg++)
            w2f[nt][kg] = *(const bf16x8*)(W2f + ((nt * 4 + kg) * 64 + lane) * 8);

    float b1r[8], b2r[4];
    #pragma unroll
    for (int nt = 0; nt < 8; nt++) b1r[nt] = b1f[nt * 16 + l15];
    #pragma unroll
    for (int nt = 0; nt < 4; nt++) b2r[nt] = b2f[nt * 16 + l15];

    for (int tile = blockIdx.x; tile < NTILE; tile += gridDim.x) {
        const int e0  = tile * 64;
        const int row = wv * 16 + l15;

        int si = srcs[e0 + row];
        int di = dsts[e0 + row];

        // A fragments: k-space [src64|dst64|ef8|pad24]
        bf16x8 af[5];
        {
            const float* sp0 = h + (size_t)si * 64 + quad * 8;
            const float* sp1 = h + (size_t)di * 64 + quad * 8;
            af[0] = cvt8(sp0);
            af[1] = cvt8(sp0 + 32);
            af[2] = cvt8(sp1);
            af[3] = cvt8(sp1 + 32);
            if (quad == 0) {
                af[4] = cvt8(efp + (size_t)(e0 + row) * 8);
            } else {
                #pragma unroll
                for (int q = 0; q < 8; q++) af[4][q] = (bf16_t)0.f;
            }
        }

        floatx4 oa[4];
        #pragma unroll
        for (int nt = 0; nt < 4; nt++) { oa[nt].x = 0.f; oa[nt].y = 0.f; oa[nt].z = 0.f; oa[nt].w = 0.f; }

        #pragma unroll
        for (int hh = 0; hh < 2; hh++) {
            // ---- GEMM1 half: hidden cols hh*64 .. hh*64+63 ----
            floatx4 acc[4];
            #pragma unroll
            for (int nt = 0; nt < 4; nt++) { acc[nt].x = 0.f; acc[nt].y = 0.f; acc[nt].z = 0.f; acc[nt].w = 0.f; }
            #pragma unroll
            for (int nt = 0; nt < 4; nt++) {
                int gnt = hh * 4 + nt;
                #pragma unroll
                for (int ks = 0; ks < 5; ks++) {
                    bf16x8 b = *(const bf16x8*)(w1s + ((gnt * 5 + ks) * 64 + lane) * 8);
                    acc[nt] = mfma16(af[ks], b, acc[nt]);
                }
            }
            // bias+relu -> per-wave half tile (C/D: col=l15, row=quad*4+r)
            #pragma unroll
            for (int nt = 0; nt < 4; nt++) {
                float bb = b1r[hh * 4 + nt];
                int col = nt * 16 + l15;
                #pragma unroll
                for (int r = 0; r < 4; r++) {
                    float v = fmaxf(acc[nt][r] + bb, 0.f);
                    hs[wv][(quad * 4 + r) * 72 + col] = (bf16_t)v;
                }
            }
            // same-wave write->read (lgkmcnt handled by compiler)

            // ---- GEMM2 partial: k = hh*64 .. hh*64+63 ----
            bf16x8 hf[2];
            {
                const bf16_t* hp = hs[wv] + l15 * 72 + quad * 8;
                hf[0] = *(const bf16x8*)(hp);
                hf[1] = *(const bf16x8*)(hp + 32);
            }
            #pragma unroll
            for (int nt = 0; nt < 4; nt++) {
                oa[nt] = mfma16(hf[0], w2f[nt][hh * 2 + 0], oa[nt]);
                oa[nt] = mfma16(hf[1], w2f[nt][hh * 2 + 1], oa[nt]);
            }
        }

        if (MODE == 0) {
            // plain coalesced stores of m (sorted edge order)
            #pragma unroll
            for (int nt = 0; nt < 4; nt++) {
                float bb = b2r[nt];
                #pragma unroll
                for (int r = 0; r < 4; r++) {
                    int orow = e0 + wv * 16 + quad * 4 + r;
                    mbuf[(size_t)orow * 64 + nt * 16 + l15] = oa[nt][r] + bb;
                }
            }
        } else {
            int4 d4 = *(const int4*)(dsts + e0 + wv * 16 + quad * 4);
            #pragma unroll
            for (int nt = 0; nt < 4; nt++) {
                int col = nt * 16 + l15;
                float bb = b2r[nt];
                float* ap = agg + col;
                int dcur = d4.x;
                float v = oa[nt][0] + bb;
                if (d4.y == dcur) v += oa[nt][1] + bb;
                else { atomicAdd(ap + (size_t)dcur * 64, v); dcur = d4.y; v = oa[nt][1] + bb; }
                if (d4.z == dcur) v += oa[nt][2] + bb;
                else { atomicAdd(ap + (size_t)dcur * 64, v); dcur = d4.z; v = oa[nt][2] + bb; }
                if (d4.w == dcur) v += oa[nt][3] + bb;
                else { atomicAdd(ap + (size_t)dcur * 64, v); dcur = d4.w; v = oa[nt][3] + bb; }
                atomicAdd(ap + (size_t)dcur * 64, v);
            }
        }
    }
}

// ---------------------------------------------------------------------------
// agg kernel: wave-per-node CSR gather-sum, lane-per-col. No atomics.
// cursor holds row-END offsets post-scatter; start = end - deg.
// ---------------------------------------------------------------------------
__global__ __launch_bounds__(256) void agg_kernel(
    const float* __restrict__ mbuf, const int* __restrict__ deg,
    const int* __restrict__ cursor, float* __restrict__ agg)
{
    const int node = blockIdx.x * 4 + (threadIdx.x >> 6);
    if (node >= NN) return;
    const int lane = threadIdx.x & 63;
    int dg  = deg[node];
    int end = cursor[node];
    int st  = end - dg;
    float s = 0.f;
    for (int e = st; e < end; e++) s += mbuf[(size_t)e * 64 + lane];
    agg[(size_t)node * 64 + lane] = s;
}

// ---------------------------------------------------------------------------
// GRU (MFMA): 64 nodes/block, 16/wave (unchanged from R5).
// ---------------------------------------------------------------------------
__global__ __launch_bounds__(256) void gru_kernel(
    const float* __restrict__ agg, const float* __restrict__ h_in,
    float* __restrict__ h_out,
    const bf16_t* __restrict__ Wxt, const bf16_t* __restrict__ Wht,
    const float* __restrict__ bg)
{
    __shared__ __attribute__((aligned(16))) float shd[64 * 68];   // 17408 B
    const int tid = threadIdx.x;
    const int n0  = blockIdx.x * 64;

    for (int idx = tid; idx < 64 * 16; idx += 256) {
        int i = idx >> 4, c = (idx & 15) * 4;
        int n = n0 + i; if (n >= NN) n = NN - 1;
        *(float4*)&shd[i * 68 + c] = *(const float4*)(h_in + (size_t)n * 64 + c);
    }
    __syncthreads();

    const int lane = tid & 63;
    const int wv   = tid >> 6;
    const int l15  = lane & 15;
    const int quad = lane >> 4;
    const int rowA = wv * 16 + l15;
    int nA = n0 + rowA; if (nA >= NN) nA = NN - 1;

    bf16x8 ax[2], ah[2];
    ax[0] = cvt8(agg + (size_t)nA * 64 + quad * 8);
    ax[1] = cvt8(agg + (size_t)nA * 64 + quad * 8 + 32);
    {
        const float* hp = shd + rowA * 68 + quad * 8;
        ah[0] = cvt8(hp);
        ah[1] = cvt8(hp + 32);
    }

    floatx4 az[4], ar[4], axh[4], ahh[4];
    #pragma unroll
    for (int nt = 0; nt < 4; nt++) {
        az[nt].x=0.f; az[nt].y=0.f; az[nt].z=0.f; az[nt].w=0.f;
        ar[nt].x=0.f; ar[nt].y=0.f; ar[nt].z=0.f; ar[nt].w=0.f;
        axh[nt].x=0.f; axh[nt].y=0.f; axh[nt].z=0.f; axh[nt].w=0.f;
        ahh[nt].x=0.f; ahh[nt].y=0.f; ahh[nt].z=0.f; ahh[nt].w=0.f;
    }
    #pragma unroll
    for (int nt = 0; nt < 4; nt++) {
        const bf16_t* bx_z = Wxt + (nt * 16 + l15) * 64 + quad * 8;
        const bf16_t* bh_z = Wht + (nt * 16 + l15) * 64 + quad * 8;
        const bf16_t* bx_r = bx_z + 64 * 64;
        const bf16_t* bh_r = bh_z + 64 * 64;
        const bf16_t* bx_h = bx_z + 128 * 64;
        const bf16_t* bh_h = bh_z + 128 * 64;
        az[nt]  = mfma16(ax[0], *(const bf16x8*)bx_z,        az[nt]);
        az[nt]  = mfma16(ax[1], *(const bf16x8*)(bx_z + 32), az[nt]);
        az[nt]  = mfma16(ah[0], *(const bf16x8*)bh_z,        az[nt]);
        az[nt]  = mfma16(ah[1], *(const bf16x8*)(bh_z + 32), az[nt]);
        ar[nt]  = mfma16(ax[0], *(const bf16x8*)bx_r,        ar[nt]);
        ar[nt]  = mfma16(ax[1], *(const bf16x8*)(bx_r + 32), ar[nt]);
        ar[nt]  = mfma16(ah[0], *(const bf16x8*)bh_r,        ar[nt]);
        ar[nt]  = mfma16(ah[1], *(const bf16x8*)(bh_r + 32), ar[nt]);
        axh[nt] = mfma16(ax[0], *(const bf16x8*)bx_h,        axh[nt]);
        axh[nt] = mfma16(ax[1], *(const bf16x8*)(bx_h + 32), axh[nt]);
        ahh[nt] = mfma16(ah[0], *(const bf16x8*)bh_h,        ahh[nt]);
        ahh[nt] = mfma16(ah[1], *(const bf16x8*)(bh_h + 32), ahh[nt]);
    }

    #pragma unroll
    for (int nt = 0; nt < 4; nt++) {
        int j = nt * 16 + l15;
        float bz = bg[j], brr = bg[64 + j], bh = bg[128 + j];
        #pragma unroll
        for (int r = 0; r < 4; r++) {
            int lrow = wv * 16 + quad * 4 + r;
            int n = n0 + lrow;
            float z  = sigm_f(az[nt][r] + bz);
            float rr = sigm_f(ar[nt][r] + brr);
            float hc = tanh_f(axh[nt][r] + bh + rr * ahh[nt][r]);
            float hold = shd[lrow * 68 + j];
            float hnew = z * hold + (1.f - z) * hc;
            if (n < NN) h_out[(size_t)n * 64 + j] = hnew;
        }
    }
}

// ---------------------------------------------------------------------------
// readout (unchanged; unroll-1 pinned).
// ---------------------------------------------------------------------------
__global__ __launch_bounds__(256) void readout_kernel(
    const float* __restrict__ h, const float* __restrict__ Wr1,
    const float* __restrict__ br1, const float* __restrict__ Wr2,
    const float* __restrict__ br2, float* __restrict__ out)
{
    __shared__ float shd[32][64];
    const int tid = threadIdx.x;
    const int nb0 = blockIdx.x * 32;

    for (int idx = tid; idx < 32 * 16; idx += 256) {
        int i = idx >> 4, c = (idx & 15) * 4;
        int n = nb0 + i;
        float4 hv = make_float4(0.f, 0.f, 0.f, 0.f);
        if (n < NN) hv = *(const float4*)(h + (size_t)n * 64 + c);
        *(float4*)&shd[i][c] = hv;
    }
    __syncthreads();

    const int j  = tid & 63;
    const int wv = tid >> 6;

    float c0[8], c1[8];
    #pragma unroll
    for (int ii = 0; ii < 8; ii++) { c0[ii] = 0.f; c1[ii] = 0.f; }

    #pragma unroll 1
    for (int k0 = 0; k0 < 64; k0 += 2) {
        float2 h2[8];
        #pragma unroll
        for (int ii = 0; ii < 8; ii++) h2[ii] = *(const float2*)&shd[wv * 8 + ii][k0];
        #pragma unroll
        for (int kk = 0; kk < 2; kk++) {
            int k = k0 + kk;
            float w0 = Wr1[k * 128 + j];
            float w1 = Wr1[k * 128 + 64 + j];
            #pragma unroll
            for (int ii = 0; ii < 8; ii++) {
                float hv = kk ? h2[ii].y : h2[ii].x;
                c0[ii] = fmaf(hv, w0, c0[ii]);
                c1[ii] = fmaf(hv, w1, c1[ii]);
            }
        }
    }

    float r2a = Wr2[j], r2b = Wr2[64 + j];
    float bb0 = br1[j], bb1 = br1[64 + j];
    float br2v = br2[0];
    #pragma unroll
    for (int ii = 0; ii < 8; ii++) {
        float p = fmaxf(c0[ii] + bb0, 0.f) * r2a + fmaxf(c1[ii] + bb1, 0.f) * r2b;
        #pragma unroll
        for (int m = 32; m >= 1; m >>= 1) p += __shfl_xor(p, m, 64);
        if (j == 0) {
            int n = nb0 + wv * 8 + ii;
            if (n < NN) out[n] = p + br2v;
        }
    }
}

// ---------------------------------------------------------------------------
extern "C" void kernel_launch(void* const* d_in, const int* in_sizes, int n_in,
                              void* d_out, int out_size, void* d_ws, size_t ws_size,
                              hipStream_t stream)
{
    const float* nf  = (const float*)d_in[0];
    const float* ef  = (const float*)d_in[1];
    const int* esrc  = (const int*)d_in[2];
    const int* edst  = (const int*)d_in[3];
    const float* Wm1 = (const float*)d_in[4];
    const float* bm1 = (const float*)d_in[5];
    const float* Wm2 = (const float*)d_in[6];
    const float* bm2 = (const float*)d_in[7];
    const float* Wx  = (const float*)d_in[8];
    const float* Wh  = (const float*)d_in[9];
    const float* bg  = (const float*)d_in[10];
    const float* Wr1 = (const float*)d_in[11];
    const float* br1 = (const float*)d_in[12];
    const float* Wr2 = (const float*)d_in[13];
    const float* br2 = (const float*)d_in[14];

    char* ws = (char*)d_ws;
    float*  hbuf   = (float*)(ws);                   // 12,800,000
    float*  agg    = (float*)(ws + 12800000);        // 12,800,000
    bf16_t* W1f    = (bf16_t*)(ws + 25600000);       // 40,960
    bf16_t* W2f    = (bf16_t*)(ws + 25640960);       // 16,384
    bf16_t* Wxt    = (bf16_t*)(ws + 25657344);       // 24,576
    bf16_t* Wht    = (bf16_t*)(ws + 25681920);       // 24,576
    int*    srcs   = (int*)(ws + 25706496);          // 1,600,000
    int*    dsts   = (int*)(ws + 27306496);          // 1,600,000
    float*  efp    = (float*)(ws + 28906496);        // 12,800,000
    int*    deg    = (int*)(ws + 41706496);          // 200,704
    int*    cursor = (int*)(ws + 41907200);          // 200,704
    int*    chunkS = (int*)(ws + 42107904);          // 1,024
    int*    chunkO = (int*)(ws + 42108928);          // 1,024
    float*  mbuf   = (float*)(ws + 42109952);        // 102,400,000
    const size_t NEEDED = 42109952ull + 102400000ull;
    const bool use_m = (ws_size >= NEEDED);

    prep_kernel<<<208, 256, 0, stream>>>(Wm1, Wm2, Wx, Wh, W1f, W2f, Wxt, Wht);

    // CSR build (same work every call)
    hipMemsetAsync(deg, 0, NPAD * 4, stream);
    hist_kernel<<<(NE + 255) / 256, 256, 0, stream>>>(edst, deg);
    scanA_kernel<<<NCH, 256, 0, stream>>>(deg, chunkS);
    scanB_kernel<<<1, 256, 0, stream>>>(chunkS, chunkO);
    scanC_kernel<<<NCH, 256, 0, stream>>>(deg, chunkO, cursor);
    scatter_kernel<<<(NE + 255) / 256, 256, 0, stream>>>(esrc, edst, ef, cursor,
                                                         srcs, dsts, efp);

    for (int t = 0; t < 2; t++) {
        const float* h_in = (t == 0) ? nf : hbuf;
        if (use_m) {
            edge_kernel<0><<<1536, 256, 0, stream>>>(h_in, efp, srcs, dsts,
                                                     W1f, W2f, bm1, bm2, mbuf, agg);
            agg_kernel<<<(NN + 3) / 4, 256, 0, stream>>>(mbuf, deg, cursor, agg);
        } else {
            hipMemsetAsync(agg, 0, (size_t)NN * 64 * 4, stream);
            edge_kernel<1><<<1536, 256, 0, stream>>>(h_in, efp, srcs, dsts,
                                                     W1f, W2f, bm1, bm2, mbuf, agg);
        }
        gru_kernel<<<(NN + 63) / 64, 256, 0, stream>>>(agg, h_in, hbuf, Wxt, Wht, bg);
    }
    readout_kernel<<<(NN + 31) / 32, 256, 0, stream>>>(hbuf, Wr1, br1, Wr2, br2,
                                                       (float*)d_out);
}

// Round 7
// 670.112 us; speedup vs baseline: 1.0259x; 1.0259x over previous
//
#include <hip/hip_runtime.h>
#include <hip/hip_bf16.h>

#define NN 50000
#define NE 400000
#define NGRP 25000         // NE/16 wave-groups
#define NCH 196            // ceil(50176/256) scan chunks
#define NPAD 50176         // NCH*256

typedef __bf16 bf16_t;
typedef __bf16 bf16x4 __attribute__((ext_vector_type(4)));
typedef __bf16 bf16x8 __attribute__((ext_vector_type(8)));
typedef float  floatx4 __attribute__((ext_vector_type(4)));

static __device__ __forceinline__ floatx4 mfma16(bf16x8 a, bf16x8 b, floatx4 c) {
    return __builtin_amdgcn_mfma_f32_16x16x32_bf16(a, b, c, 0, 0, 0);
}
static __device__ __forceinline__ float sigm_f(float x) {
    return 1.f / (1.f + __expf(-x));
}
static __device__ __forceinline__ float tanh_f(float x) {
    return 1.f - 2.f / (__expf(2.f * x) + 1.f);
}
static __device__ __forceinline__ bf16x8 cvt8(const float* sp) {
    float4 f0 = *(const float4*)sp;
    float4 f1 = *(const float4*)(sp + 4);
    bf16x8 v;
    v[0] = (bf16_t)f0.x; v[1] = (bf16_t)f0.y; v[2] = (bf16_t)f0.z; v[3] = (bf16_t)f0.w;
    v[4] = (bf16_t)f1.x; v[5] = (bf16_t)f1.y; v[6] = (bf16_t)f1.z; v[7] = (bf16_t)f1.w;
    return v;
}

// ---------------------------------------------------------------------------
// prep: weights into MFMA-fragment-linear bf16 order (R6 layout, verified).
// ---------------------------------------------------------------------------
__global__ __launch_bounds__(256) void prep_kernel(
    const float* __restrict__ Wm1, const float* __restrict__ Wm2,
    const float* __restrict__ Wx,  const float* __restrict__ Wh,
    bf16_t* __restrict__ W1f, bf16_t* __restrict__ W2f,
    bf16_t* __restrict__ Wxt, bf16_t* __restrict__ Wht)
{
    int u = blockIdx.x * 256 + threadIdx.x;
    if (u < 20480) {
        int j = u & 7, l = (u >> 3) & 63, rem = u >> 9;   // rem 0..39
        int ks = rem % 5, nt = rem / 5;
        int n = nt * 16 + (l & 15);
        int k = ks * 32 + (l >> 4) * 8 + j;
        W1f[u] = (k < 136) ? (bf16_t)Wm1[k * 128 + n] : (bf16_t)0.f;
        return;
    }
    u -= 20480;
    if (u < 8192) {
        int j = u & 7, l = (u >> 3) & 63, rem = u >> 9;   // rem 0..15
        int kg = rem & 3, nt = rem >> 2;
        int n = nt * 16 + (l & 15);
        int k = kg * 32 + (l >> 4) * 8 + j;
        W2f[u] = (bf16_t)Wm2[k * 64 + n];
        return;
    }
    u -= 8192;
    if (u < 12288) {
        int n = u >> 6, k = u & 63;
        Wxt[u] = (bf16_t)Wx[k * 192 + n];
        return;
    }
    u -= 12288;
    if (u < 12288) {
        int n = u >> 6, k = u & 63;
        Wht[u] = (bf16_t)Wh[k * 192 + n];
    }
}

// hb0: bf16 copy of node_feats (step-0 edge input). 800000 threads x 4 elems.
__global__ __launch_bounds__(256) void hb0_kernel(
    const float* __restrict__ nf, bf16_t* __restrict__ hb)
{
    int t = blockIdx.x * 256 + threadIdx.x;
    float4 v = *(const float4*)(nf + (size_t)t * 4);
    bf16x4 o;
    o[0] = (bf16_t)v.x; o[1] = (bf16_t)v.y; o[2] = (bf16_t)v.z; o[3] = (bf16_t)v.w;
    *(bf16x4*)(hb + (size_t)t * 4) = o;
}

// ---------------------------------------------------------------------------
// CSR build: hist -> scan -> scatter (permute srcs/dsts/ef->bf16, dst-sorted)
// ---------------------------------------------------------------------------
__global__ __launch_bounds__(256) void hist_kernel(
    const int* __restrict__ edst, int* __restrict__ deg)
{
    int e = blockIdx.x * 256 + threadIdx.x;
    if (e < NE) atomicAdd(&deg[edst[e]], 1);
}

__global__ __launch_bounds__(256) void scanA_kernel(
    const int* __restrict__ deg, int* __restrict__ chunkSums)
{
    __shared__ int s[256];
    int i = blockIdx.x * 256 + threadIdx.x;
    s[threadIdx.x] = deg[i];
    __syncthreads();
    for (int st = 128; st >= 1; st >>= 1) {
        if (threadIdx.x < st) s[threadIdx.x] += s[threadIdx.x + st];
        __syncthreads();
    }
    if (threadIdx.x == 0) chunkSums[blockIdx.x] = s[0];
}

__global__ __launch_bounds__(256) void scanB_kernel(
    const int* __restrict__ chunkSums, int* __restrict__ chunkOff)
{
    __shared__ int s[256];
    int t = threadIdx.x;
    int v = (t < NCH) ? chunkSums[t] : 0;
    s[t] = v;
    __syncthreads();
    for (int st = 1; st < 256; st <<= 1) {
        int add = (t >= st) ? s[t - st] : 0;
        __syncthreads();
        s[t] += add;
        __syncthreads();
    }
    if (t < NCH) chunkOff[t] = s[t] - v;   // exclusive
}

__global__ __launch_bounds__(256) void scanC_kernel(
    const int* __restrict__ deg, const int* __restrict__ chunkOff,
    int* __restrict__ cursor)
{
    __shared__ int s[256];
    int t = threadIdx.x;
    int i = blockIdx.x * 256 + t;
    int v = deg[i];
    s[t] = v;
    __syncthreads();
    for (int st = 1; st < 256; st <<= 1) {
        int add = (t >= st) ? s[t - st] : 0;
        __syncthreads();
        s[t] += add;
        __syncthreads();
    }
    cursor[i] = chunkOff[blockIdx.x] + s[t] - v;   // exclusive
}

__global__ __launch_bounds__(256) void scatter_kernel(
    const int* __restrict__ esrc, const int* __restrict__ edst,
    const float* __restrict__ ef,
    int* __restrict__ cursor, int* __restrict__ srcs, int* __restrict__ dsts,
    bf16_t* __restrict__ efpb)
{
    int e = blockIdx.x * 256 + threadIdx.x;
    if (e >= NE) return;
    int d = edst[e];
    int p = atomicAdd(&cursor[d], 1);
    srcs[p] = esrc[e];
    dsts[p] = d;
    float4 a = *(const float4*)(ef + (size_t)e * 8);
    float4 b = *(const float4*)(ef + (size_t)e * 8 + 4);
    bf16x8 v;
    v[0] = (bf16_t)a.x; v[1] = (bf16_t)a.y; v[2] = (bf16_t)a.z; v[3] = (bf16_t)a.w;
    v[4] = (bf16_t)b.x; v[5] = (bf16_t)b.y; v[6] = (bf16_t)b.z; v[7] = (bf16_t)b.w;
    *(bf16x8*)(efpb + (size_t)p * 8) = v;
}

// ---------------------------------------------------------------------------
// edge kernel v7: 512-thread blocks (8 waves share one 41KB W1 LDS copy ->
// LDS 50.2KB/block -> 16 waves/CU; R5's 75KB gave ~3.4 waves/CU and pure
// latency exposure). bf16 inputs (hb/efpb): no cvt, half the gather bytes.
// Quarter-tile GEMM1 (hq = 16x36/wave). W2 frags + biases in registers.
// Epilogue: R5 merged atomics (R6 proved materializing m is far worse).
// ---------------------------------------------------------------------------
__global__ __launch_bounds__(512, 4) void edge_kernel(
    const bf16_t* __restrict__ hb, const bf16_t* __restrict__ efpb,
    const int* __restrict__ srcs, const int* __restrict__ dsts,
    const bf16_t* __restrict__ W1f, const bf16_t* __restrict__ W2f,
    const float* __restrict__ b1f, const float* __restrict__ b2f,
    float* __restrict__ agg)
{
    __shared__ __attribute__((aligned(16))) bf16_t w1s[20480];     // 40960 B
    __shared__ __attribute__((aligned(16))) bf16_t hq[8][16 * 36]; // 9216 B

    const int tid = threadIdx.x;
    {
        const uint4* s1 = (const uint4*)W1f;
        uint4* d1 = (uint4*)w1s;
        #pragma unroll
        for (int i = 0; i < 5; i++) d1[tid + i * 512] = s1[tid + i * 512];
    }
    __syncthreads();

    const int lane = tid & 63;
    const int wv   = tid >> 6;      // 0..7
    const int l15  = lane & 15;
    const int quad = lane >> 4;

    // W2 fragments in registers (frag-linear, coalesced)
    bf16x8 w2f[4][4];
    #pragma unroll
    for (int nt = 0; nt < 4; nt++)
        #pragma unroll
        for (int kg = 0; kg < 4; kg++)
            w2f[nt][kg] = *(const bf16x8*)(W2f + ((nt * 4 + kg) * 64 + lane) * 8);

    float b1r[8], b2r[4];
    #pragma unroll
    for (int nt = 0; nt < 8; nt++) b1r[nt] = b1f[nt * 16 + l15];
    #pragma unroll
    for (int nt = 0; nt < 4; nt++) b2r[nt] = b2f[nt * 16 + l15];

    const int wstride = gridDim.x * 8;
    for (int g = blockIdx.x * 8 + wv; g < NGRP; g += wstride) {
        const int row = g * 16 + l15;
        int si = srcs[row];
        int di = dsts[row];

        // A fragments (bf16 direct): k-space [src64|dst64|ef8|pad24]
        bf16x8 af[5];
        {
            const bf16_t* sp = hb + (size_t)si * 64 + quad * 8;
            const bf16_t* dp = hb + (size_t)di * 64 + quad * 8;
            af[0] = *(const bf16x8*)sp;
            af[1] = *(const bf16x8*)(sp + 32);
            af[2] = *(const bf16x8*)dp;
            af[3] = *(const bf16x8*)(dp + 32);
            if (quad == 0) {
                af[4] = *(const bf16x8*)(efpb + (size_t)row * 8);
            } else {
                #pragma unroll
                for (int q = 0; q < 8; q++) af[4][q] = (bf16_t)0.f;
            }
        }

        floatx4 oa[4];
        #pragma unroll
        for (int nt = 0; nt < 4; nt++) { oa[nt].x = 0.f; oa[nt].y = 0.f; oa[nt].z = 0.f; oa[nt].w = 0.f; }

        #pragma unroll
        for (int q = 0; q < 4; q++) {
            // GEMM1 quarter: hidden cols q*32 .. q*32+31
            floatx4 acc[2];
            #pragma unroll
            for (int nt = 0; nt < 2; nt++) { acc[nt].x = 0.f; acc[nt].y = 0.f; acc[nt].z = 0.f; acc[nt].w = 0.f; }
            #pragma unroll
            for (int nt = 0; nt < 2; nt++) {
                int gnt = q * 2 + nt;
                #pragma unroll
                for (int ks = 0; ks < 5; ks++) {
                    bf16x8 b = *(const bf16x8*)(w1s + ((gnt * 5 + ks) * 64 + lane) * 8);
                    acc[nt] = mfma16(af[ks], b, acc[nt]);
                }
            }
            // bias+relu -> per-wave quarter tile (C/D: col=l15, row=quad*4+r)
            #pragma unroll
            for (int nt = 0; nt < 2; nt++) {
                float bb = b1r[q * 2 + nt];
                #pragma unroll
                for (int r = 0; r < 4; r++) {
                    float v = fmaxf(acc[nt][r] + bb, 0.f);
                    hq[wv][(quad * 4 + r) * 36 + nt * 16 + l15] = (bf16_t)v;
                }
            }
            // same-wave write->read (compiler lgkmcnt)
            bf16x8 hf = *(const bf16x8*)(hq[wv] + l15 * 36 + quad * 8);
            #pragma unroll
            for (int nt = 0; nt < 4; nt++)
                oa[nt] = mfma16(hf, w2f[nt][q], oa[nt]);
        }

        // merged atomics over sorted dsts (m[e] = oa + b2)
        int4 d4 = *(const int4*)(dsts + g * 16 + quad * 4);
        #pragma unroll
        for (int nt = 0; nt < 4; nt++) {
            int col = nt * 16 + l15;
            float bb = b2r[nt];
            float* ap = agg + col;
            int dcur = d4.x;
            float v = oa[nt][0] + bb;
            if (d4.y == dcur) v += oa[nt][1] + bb;
            else { atomicAdd(ap + (size_t)dcur * 64, v); dcur = d4.y; v = oa[nt][1] + bb; }
            if (d4.z == dcur) v += oa[nt][2] + bb;
            else { atomicAdd(ap + (size_t)dcur * 64, v); dcur = d4.z; v = oa[nt][2] + bb; }
            if (d4.w == dcur) v += oa[nt][3] + bb;
            else { atomicAdd(ap + (size_t)dcur * 64, v); dcur = d4.w; v = oa[nt][3] + bb; }
            atomicAdd(ap + (size_t)dcur * 64, v);
        }
    }
}

// ---------------------------------------------------------------------------
// GRU (MFMA): 64 nodes/block, 16/wave. Also emits bf16 h for next edge step.
// ---------------------------------------------------------------------------
__global__ __launch_bounds__(256) void gru_kernel(
    const float* __restrict__ agg, const float* __restrict__ h_in,
    float* __restrict__ h_out, bf16_t* __restrict__ hb_out,
    const bf16_t* __restrict__ Wxt, const bf16_t* __restrict__ Wht,
    const float* __restrict__ bg)
{
    __shared__ __attribute__((aligned(16))) float shd[64 * 68];   // 17408 B
    const int tid = threadIdx.x;
    const int n0  = blockIdx.x * 64;

    for (int idx = tid; idx < 64 * 16; idx += 256) {
        int i = idx >> 4, c = (idx & 15) * 4;
        int n = n0 + i; if (n >= NN) n = NN - 1;
        *(float4*)&shd[i * 68 + c] = *(const float4*)(h_in + (size_t)n * 64 + c);
    }
    __syncthreads();

    const int lane = tid & 63;
    const int wv   = tid >> 6;
    const int l15  = lane & 15;
    const int quad = lane >> 4;
    const int rowA = wv * 16 + l15;
    int nA = n0 + rowA; if (nA >= NN) nA = NN - 1;

    bf16x8 ax[2], ah[2];
    ax[0] = cvt8(agg + (size_t)nA * 64 + quad * 8);
    ax[1] = cvt8(agg + (size_t)nA * 64 + quad * 8 + 32);
    {
        const float* hp = shd + rowA * 68 + quad * 8;
        ah[0] = cvt8(hp);
        ah[1] = cvt8(hp + 32);
    }

    floatx4 az[4], ar[4], axh[4], ahh[4];
    #pragma unroll
    for (int nt = 0; nt < 4; nt++) {
        az[nt].x=0.f; az[nt].y=0.f; az[nt].z=0.f; az[nt].w=0.f;
        ar[nt].x=0.f; ar[nt].y=0.f; ar[nt].z=0.f; ar[nt].w=0.f;
        axh[nt].x=0.f; axh[nt].y=0.f; axh[nt].z=0.f; axh[nt].w=0.f;
        ahh[nt].x=0.f; ahh[nt].y=0.f; ahh[nt].z=0.f; ahh[nt].w=0.f;
    }
    #pragma unroll
    for (int nt = 0; nt < 4; nt++) {
        const bf16_t* bx_z = Wxt + (nt * 16 + l15) * 64 + quad * 8;
        const bf16_t* bh_z = Wht + (nt * 16 + l15) * 64 + quad * 8;
        const bf16_t* bx_r = bx_z + 64 * 64;
        const bf16_t* bh_r = bh_z + 64 * 64;
        const bf16_t* bx_h = bx_z + 128 * 64;
        const bf16_t* bh_h = bh_z + 128 * 64;
        az[nt]  = mfma16(ax[0], *(const bf16x8*)bx_z,        az[nt]);
        az[nt]  = mfma16(ax[1], *(const bf16x8*)(bx_z + 32), az[nt]);
        az[nt]  = mfma16(ah[0], *(const bf16x8*)bh_z,        az[nt]);
        az[nt]  = mfma16(ah[1], *(const bf16x8*)(bh_z + 32), az[nt]);
        ar[nt]  = mfma16(ax[0], *(const bf16x8*)bx_r,        ar[nt]);
        ar[nt]  = mfma16(ax[1], *(const bf16x8*)(bx_r + 32), ar[nt]);
        ar[nt]  = mfma16(ah[0], *(const bf16x8*)bh_r,        ar[nt]);
        ar[nt]  = mfma16(ah[1], *(const bf16x8*)(bh_r + 32), ar[nt]);
        axh[nt] = mfma16(ax[0], *(const bf16x8*)bx_h,        axh[nt]);
        axh[nt] = mfma16(ax[1], *(const bf16x8*)(bx_h + 32), axh[nt]);
        ahh[nt] = mfma16(ah[0], *(const bf16x8*)bh_h,        ahh[nt]);
        ahh[nt] = mfma16(ah[1], *(const bf16x8*)(bh_h + 32), ahh[nt]);
    }

    #pragma unroll
    for (int nt = 0; nt < 4; nt++) {
        int j = nt * 16 + l15;
        float bz = bg[j], brr = bg[64 + j], bh = bg[128 + j];
        #pragma unroll
        for (int r = 0; r < 4; r++) {
            int lrow = wv * 16 + quad * 4 + r;
            int n = n0 + lrow;
            float z  = sigm_f(az[nt][r] + bz);
            float rr = sigm_f(ar[nt][r] + brr);
            float hc = tanh_f(axh[nt][r] + bh + rr * ahh[nt][r]);
            float hold = shd[lrow * 68 + j];
            float hnew = z * hold + (1.f - z) * hc;
            if (n < NN) {
                h_out[(size_t)n * 64 + j]  = hnew;
                hb_out[(size_t)n * 64 + j] = (bf16_t)hnew;
            }
        }
    }
}

// ---------------------------------------------------------------------------
// readout (unchanged; unroll-1 pinned against the R1 spill).
// ---------------------------------------------------------------------------
__global__ __launch_bounds__(256) void readout_kernel(
    const float* __restrict__ h, const float* __restrict__ Wr1,
    const float* __restrict__ br1, const float* __restrict__ Wr2,
    const float* __restrict__ br2, float* __restrict__ out)
{
    __shared__ float shd[32][64];
    const int tid = threadIdx.x;
    const int nb0 = blockIdx.x * 32;

    for (int idx = tid; idx < 32 * 16; idx += 256) {
        int i = idx >> 4, c = (idx & 15) * 4;
        int n = nb0 + i;
        float4 hv = make_float4(0.f, 0.f, 0.f, 0.f);
        if (n < NN) hv = *(const float4*)(h + (size_t)n * 64 + c);
        *(float4*)&shd[i][c] = hv;
    }
    __syncthreads();

    const int j  = tid & 63;
    const int wv = tid >> 6;

    float c0[8], c1[8];
    #pragma unroll
    for (int ii = 0; ii < 8; ii++) { c0[ii] = 0.f; c1[ii] = 0.f; }

    #pragma unroll 1
    for (int k0 = 0; k0 < 64; k0 += 2) {
        float2 h2[8];
        #pragma unroll
        for (int ii = 0; ii < 8; ii++) h2[ii] = *(const float2*)&shd[wv * 8 + ii][k0];
        #pragma unroll
        for (int kk = 0; kk < 2; kk++) {
            int k = k0 + kk;
            float w0 = Wr1[k * 128 + j];
            float w1 = Wr1[k * 128 + 64 + j];
            #pragma unroll
            for (int ii = 0; ii < 8; ii++) {
                float hv = kk ? h2[ii].y : h2[ii].x;
                c0[ii] = fmaf(hv, w0, c0[ii]);
                c1[ii] = fmaf(hv, w1, c1[ii]);
            }
        }
    }

    float r2a = Wr2[j], r2b = Wr2[64 + j];
    float bb0 = br1[j], bb1 = br1[64 + j];
    float br2v = br2[0];
    #pragma unroll
    for (int ii = 0; ii < 8; ii++) {
        float p = fmaxf(c0[ii] + bb0, 0.f) * r2a + fmaxf(c1[ii] + bb1, 0.f) * r2b;
        #pragma unroll
        for (int m = 32; m >= 1; m >>= 1) p += __shfl_xor(p, m, 64);
        if (j == 0) {
            int n = nb0 + wv * 8 + ii;
            if (n < NN) out[n] = p + br2v;
        }
    }
}

// ---------------------------------------------------------------------------
extern "C" void kernel_launch(void* const* d_in, const int* in_sizes, int n_in,
                              void* d_out, int out_size, void* d_ws, size_t ws_size,
                              hipStream_t stream)
{
    const float* nf  = (const float*)d_in[0];
    const float* ef  = (const float*)d_in[1];
    const int* esrc  = (const int*)d_in[2];
    const int* edst  = (const int*)d_in[3];
    const float* Wm1 = (const float*)d_in[4];
    const float* bm1 = (const float*)d_in[5];
    const float* Wm2 = (const float*)d_in[6];
    const float* bm2 = (const float*)d_in[7];
    const float* Wx  = (const float*)d_in[8];
    const float* Wh  = (const float*)d_in[9];
    const float* bg  = (const float*)d_in[10];
    const float* Wr1 = (const float*)d_in[11];
    const float* br1 = (const float*)d_in[12];
    const float* Wr2 = (const float*)d_in[13];
    const float* br2 = (const float*)d_in[14];

    char* ws = (char*)d_ws;
    float*  hbuf   = (float*)(ws);                   // 12,800,000
    float*  agg    = (float*)(ws + 12800000);        // 12,800,000
    bf16_t* hb     = (bf16_t*)(ws + 25600000);       // 6,400,000
    bf16_t* W1f    = (bf16_t*)(ws + 32000000);       // 40,960
    bf16_t* W2f    = (bf16_t*)(ws + 32040960);       // 16,384
    bf16_t* Wxt    = (bf16_t*)(ws + 32057344);       // 24,576
    bf16_t* Wht    = (bf16_t*)(ws + 32081920);       // 24,576
    int*    srcs   = (int*)(ws + 32106496);          // 1,600,000
    int*    dsts   = (int*)(ws + 33706496);          // 1,600,000
    bf16_t* efpb   = (bf16_t*)(ws + 35306496);       // 6,400,000
    int*    deg    = (int*)(ws + 41706496);          // 200,704
    int*    cursor = (int*)(ws + 41907200);          // 200,704
    int*    chunkS = (int*)(ws + 42107904);          // 1,024
    int*    chunkO = (int*)(ws + 42108928);          // 1,024

    prep_kernel<<<208, 256, 0, stream>>>(Wm1, Wm2, Wx, Wh, W1f, W2f, Wxt, Wht);
    hb0_kernel<<<3125, 256, 0, stream>>>(nf, hb);

    // CSR build (same work every call)
    hipMemsetAsync(deg, 0, NPAD * 4, stream);
    hist_kernel<<<(NE + 255) / 256, 256, 0, stream>>>(edst, deg);
    scanA_kernel<<<NCH, 256, 0, stream>>>(deg, chunkS);
    scanB_kernel<<<1, 256, 0, stream>>>(chunkS, chunkO);
    scanC_kernel<<<NCH, 256, 0, stream>>>(deg, chunkO, cursor);
    scatter_kernel<<<(NE + 255) / 256, 256, 0, stream>>>(esrc, edst, ef, cursor,
                                                         srcs, dsts, efpb);

    for (int t = 0; t < 2; t++) {
        const float* h_in = (t == 0) ? nf : hbuf;
        hipMemsetAsync(agg, 0, (size_t)NN * 64 * 4, stream);
        edge_kernel<<<768, 512, 0, stream>>>(hb, efpb, srcs, dsts,
                                             W1f, W2f, bm1, bm2, agg);
        gru_kernel<<<(NN + 63) / 64, 256, 0, stream>>>(agg, h_in, hbuf, hb,
                                                       Wxt, Wht, bg);
    }
    readout_kernel<<<(NN + 31) / 32, 256, 0, stream>>>(hbuf, Wr1, br1, Wr2, br2,
                                                       (float*)d_out);
}

// Round 8
// 385.925 us; speedup vs baseline: 1.7814x; 1.7364x over previous
//
#include <hip/hip_runtime.h>
#include <hip/hip_bf16.h>

#define NN 50000
#define NE 400000
#define NTILE 6250         // NE/64 edge tiles
#define NCH 196            // ceil(50176/256) scan chunks
#define NPAD 50176         // NCH*256

typedef __bf16 bf16_t;
typedef __bf16 bf16x4 __attribute__((ext_vector_type(4)));
typedef __bf16 bf16x8 __attribute__((ext_vector_type(8)));
typedef float  floatx4 __attribute__((ext_vector_type(4)));

static __device__ __forceinline__ floatx4 mfma16(bf16x8 a, bf16x8 b, floatx4 c) {
    return __builtin_amdgcn_mfma_f32_16x16x32_bf16(a, b, c, 0, 0, 0);
}
static __device__ __forceinline__ float sigm_f(float x) {
    return 1.f / (1.f + __expf(-x));
}
static __device__ __forceinline__ float tanh_f(float x) {
    return 1.f - 2.f / (__expf(2.f * x) + 1.f);
}
static __device__ __forceinline__ bf16x8 cvt8(const float* sp) {
    float4 f0 = *(const float4*)sp;
    float4 f1 = *(const float4*)(sp + 4);
    bf16x8 v;
    v[0] = (bf16_t)f0.x; v[1] = (bf16_t)f0.y; v[2] = (bf16_t)f0.z; v[3] = (bf16_t)f0.w;
    v[4] = (bf16_t)f1.x; v[5] = (bf16_t)f1.y; v[6] = (bf16_t)f1.z; v[7] = (bf16_t)f1.w;
    return v;
}

// ---------------------------------------------------------------------------
// prep: weights into MFMA-fragment-linear bf16 order.
// W1f[((nt*5+ks)*64+l)*8+j] = W1[k=ks*32+(l>>4)*8+j][n=nt*16+(l&15)], k<136 else 0
// W2f[((nt*4+kg)*64+l)*8+j] = W2[k=kg*32+(l>>4)*8+j][n=nt*16+(l&15)]
// ---------------------------------------------------------------------------
__global__ __launch_bounds__(256) void prep_kernel(
    const float* __restrict__ Wm1, const float* __restrict__ Wm2,
    const float* __restrict__ Wx,  const float* __restrict__ Wh,
    bf16_t* __restrict__ W1f, bf16_t* __restrict__ W2f,
    bf16_t* __restrict__ Wxt, bf16_t* __restrict__ Wht)
{
    int u = blockIdx.x * 256 + threadIdx.x;
    if (u < 20480) {
        int j = u & 7, l = (u >> 3) & 63, rem = u >> 9;   // rem 0..39
        int ks = rem % 5, nt = rem / 5;
        int n = nt * 16 + (l & 15);
        int k = ks * 32 + (l >> 4) * 8 + j;
        W1f[u] = (k < 136) ? (bf16_t)Wm1[k * 128 + n] : (bf16_t)0.f;
        return;
    }
    u -= 20480;
    if (u < 8192) {
        int j = u & 7, l = (u >> 3) & 63, rem = u >> 9;   // rem 0..15
        int kg = rem & 3, nt = rem >> 2;
        int n = nt * 16 + (l & 15);
        int k = kg * 32 + (l >> 4) * 8 + j;
        W2f[u] = (bf16_t)Wm2[k * 64 + n];
        return;
    }
    u -= 8192;
    if (u < 12288) {
        int n = u >> 6, k = u & 63;
        Wxt[u] = (bf16_t)Wx[k * 192 + n];
        return;
    }
    u -= 12288;
    if (u < 12288) {
        int n = u >> 6, k = u & 63;
        Wht[u] = (bf16_t)Wh[k * 192 + n];
    }
}

// hb0: bf16 copy of node_feats (step-0 edge input).
__global__ __launch_bounds__(256) void hb0_kernel(
    const float* __restrict__ nf, bf16_t* __restrict__ hb)
{
    int t = blockIdx.x * 256 + threadIdx.x;
    float4 v = *(const float4*)(nf + (size_t)t * 4);
    bf16x4 o;
    o[0] = (bf16_t)v.x; o[1] = (bf16_t)v.y; o[2] = (bf16_t)v.z; o[3] = (bf16_t)v.w;
    *(bf16x4*)(hb + (size_t)t * 4) = o;
}

// ---------------------------------------------------------------------------
// CSR build: hist -> scan -> scatter (permute srcs/dsts/ef->bf16, dst-sorted)
// ---------------------------------------------------------------------------
__global__ __launch_bounds__(256) void hist_kernel(
    const int* __restrict__ edst, int* __restrict__ deg)
{
    int e = blockIdx.x * 256 + threadIdx.x;
    if (e < NE) atomicAdd(&deg[edst[e]], 1);
}

__global__ __launch_bounds__(256) void scanA_kernel(
    const int* __restrict__ deg, int* __restrict__ chunkSums)
{
    __shared__ int s[256];
    int i = blockIdx.x * 256 + threadIdx.x;
    s[threadIdx.x] = deg[i];
    __syncthreads();
    for (int st = 128; st >= 1; st >>= 1) {
        if (threadIdx.x < st) s[threadIdx.x] += s[threadIdx.x + st];
        __syncthreads();
    }
    if (threadIdx.x == 0) chunkSums[blockIdx.x] = s[0];
}

__global__ __launch_bounds__(256) void scanB_kernel(
    const int* __restrict__ chunkSums, int* __restrict__ chunkOff)
{
    __shared__ int s[256];
    int t = threadIdx.x;
    int v = (t < NCH) ? chunkSums[t] : 0;
    s[t] = v;
    __syncthreads();
    for (int st = 1; st < 256; st <<= 1) {
        int add = (t >= st) ? s[t - st] : 0;
        __syncthreads();
        s[t] += add;
        __syncthreads();
    }
    if (t < NCH) chunkOff[t] = s[t] - v;   // exclusive
}

__global__ __launch_bounds__(256) void scanC_kernel(
    const int* __restrict__ deg, const int* __restrict__ chunkOff,
    int* __restrict__ cursor)
{
    __shared__ int s[256];
    int t = threadIdx.x;
    int i = blockIdx.x * 256 + t;
    int v = deg[i];
    s[t] = v;
    __syncthreads();
    for (int st = 1; st < 256; st <<= 1) {
        int add = (t >= st) ? s[t - st] : 0;
        __syncthreads();
        s[t] += add;
        __syncthreads();
    }
    cursor[i] = chunkOff[blockIdx.x] + s[t] - v;   // exclusive
}

__global__ __launch_bounds__(256) void scatter_kernel(
    const int* __restrict__ esrc, const int* __restrict__ edst,
    const float* __restrict__ ef,
    int* __restrict__ cursor, int* __restrict__ srcs, int* __restrict__ dsts,
    bf16_t* __restrict__ efpb)
{
    int e = blockIdx.x * 256 + threadIdx.x;
    if (e >= NE) return;
    int d = edst[e];
    int p = atomicAdd(&cursor[d], 1);
    srcs[p] = esrc[e];
    dsts[p] = d;
    float4 a = *(const float4*)(ef + (size_t)e * 8);
    float4 b = *(const float4*)(ef + (size_t)e * 8 + 4);
    bf16x8 v;
    v[0] = (bf16_t)a.x; v[1] = (bf16_t)a.y; v[2] = (bf16_t)a.z; v[3] = (bf16_t)a.w;
    v[4] = (bf16_t)b.x; v[5] = (bf16_t)b.y; v[6] = (bf16_t)b.z; v[7] = (bf16_t)b.w;
    *(bf16x8*)(efpb + (size_t)p * 8) = v;
}

// ---------------------------------------------------------------------------
// edge kernel v8: R5 shell repaired. 256-thr blocks, 64 sorted edges/tile,
// 16/wave. W1+W2 in frag-linear LDS (lane-linear b128 -> conflict-free).
// NO register weight arrays, NO launch-bounds cap (R7: bounds-induced spill
// of w2f = 418MB scratch traffic). Software-pipelined: next tile's idx at
// loop top, next tile's A-frags loaded BEFORE the epilogue atomics so the
// atomics' slow retire stays out of the next tile's vmcnt wait chain.
// ---------------------------------------------------------------------------
__global__ __launch_bounds__(256) void edge_kernel(
    const bf16_t* __restrict__ hb, const bf16_t* __restrict__ efpb,
    const int* __restrict__ srcs, const int* __restrict__ dsts,
    const bf16_t* __restrict__ W1f, const bf16_t* __restrict__ W2f,
    const float* __restrict__ b1f, const float* __restrict__ b2f,
    float* __restrict__ agg)
{
    __shared__ __attribute__((aligned(16))) bf16_t w1s[20480];     // 40960 B
    __shared__ __attribute__((aligned(16))) bf16_t w2s[8192];      // 16384 B
    __shared__ __attribute__((aligned(16))) bf16_t hq[4][16 * 36]; //  4608 B

    const int tid = threadIdx.x;
    {
        const uint4* s1 = (const uint4*)W1f;
        uint4* d1 = (uint4*)w1s;
        #pragma unroll
        for (int i = 0; i < 10; i++) d1[tid + i * 256] = s1[tid + i * 256];
        const uint4* s2 = (const uint4*)W2f;
        uint4* d2 = (uint4*)w2s;
        #pragma unroll
        for (int i = 0; i < 4; i++) d2[tid + i * 256] = s2[tid + i * 256];
    }
    __syncthreads();

    const int lane = tid & 63;
    const int wv   = tid >> 6;
    const int l15  = lane & 15;
    const int quad = lane >> 4;

    float b1r[8], b2r[4];
    #pragma unroll
    for (int nt = 0; nt < 8; nt++) b1r[nt] = b1f[nt * 16 + l15];
    #pragma unroll
    for (int nt = 0; nt < 4; nt++) b2r[nt] = b2f[nt * 16 + l15];

    const int G = gridDim.x;
    int tile = blockIdx.x;
    if (tile >= NTILE) return;

    // prefetch tile-0 operands
    bf16x8 af[5];
    int4 d4;
    {
        int row = tile * 64 + wv * 16 + l15;
        int si = srcs[row], di = dsts[row];
        const bf16_t* sp = hb + (size_t)si * 64 + quad * 8;
        const bf16_t* dp = hb + (size_t)di * 64 + quad * 8;
        af[0] = *(const bf16x8*)sp;  af[1] = *(const bf16x8*)(sp + 32);
        af[2] = *(const bf16x8*)dp;  af[3] = *(const bf16x8*)(dp + 32);
        if (quad == 0) {
            af[4] = *(const bf16x8*)(efpb + (size_t)row * 8);
        } else {
            #pragma unroll
            for (int q = 0; q < 8; q++) af[4][q] = (bf16_t)0.f;
        }
        d4 = *(const int4*)(dsts + tile * 64 + wv * 16 + quad * 4);
    }

    while (true) {
        // next-tile index prefetch (latency covered by this tile's compute)
        int ntile = tile + G;
        int ptile = (ntile < NTILE) ? ntile : tile;      // clamped, in-bounds
        int prow  = ptile * 64 + wv * 16 + l15;
        int si_n = srcs[prow], di_n = dsts[prow];
        int4 d4_n = *(const int4*)(dsts + ptile * 64 + wv * 16 + quad * 4);

        // ---- GEMM1/GEMM2 in four 32-col quarters ----
        floatx4 oa[4];
        #pragma unroll
        for (int nt = 0; nt < 4; nt++) { oa[nt].x = 0.f; oa[nt].y = 0.f; oa[nt].z = 0.f; oa[nt].w = 0.f; }

        #pragma unroll
        for (int q = 0; q < 4; q++) {
            floatx4 acc[2];
            #pragma unroll
            for (int nt = 0; nt < 2; nt++) { acc[nt].x = 0.f; acc[nt].y = 0.f; acc[nt].z = 0.f; acc[nt].w = 0.f; }
            #pragma unroll
            for (int nt = 0; nt < 2; nt++) {
                int gnt = q * 2 + nt;
                #pragma unroll
                for (int ks = 0; ks < 5; ks++) {
                    bf16x8 b = *(const bf16x8*)(w1s + ((gnt * 5 + ks) * 64 + lane) * 8);
                    acc[nt] = mfma16(af[ks], b, acc[nt]);
                }
            }
            // bias+relu -> per-wave quarter tile (C/D: col=l15, row=quad*4+r)
            #pragma unroll
            for (int nt = 0; nt < 2; nt++) {
                float bb = b1r[q * 2 + nt];
                #pragma unroll
                for (int r = 0; r < 4; r++) {
                    float v = fmaxf(acc[nt][r] + bb, 0.f);
                    hq[wv][(quad * 4 + r) * 36 + nt * 16 + l15] = (bf16_t)v;
                }
            }
            // same-wave write->read (compiler lgkmcnt)
            bf16x8 hf = *(const bf16x8*)(hq[wv] + l15 * 36 + quad * 8);
            #pragma unroll
            for (int nt = 0; nt < 4; nt++) {
                bf16x8 w2 = *(const bf16x8*)(w2s + ((nt * 4 + q) * 64 + lane) * 8);
                oa[nt] = mfma16(hf, w2, oa[nt]);
            }
        }

        // ---- prefetch next-tile A fragments BEFORE atomics ----
        bf16x8 af_n[5];
        {
            const bf16_t* sp = hb + (size_t)si_n * 64 + quad * 8;
            const bf16_t* dp = hb + (size_t)di_n * 64 + quad * 8;
            af_n[0] = *(const bf16x8*)sp;  af_n[1] = *(const bf16x8*)(sp + 32);
            af_n[2] = *(const bf16x8*)dp;  af_n[3] = *(const bf16x8*)(dp + 32);
            if (quad == 0) {
                af_n[4] = *(const bf16x8*)(efpb + (size_t)prow * 8);
            } else {
                #pragma unroll
                for (int q = 0; q < 8; q++) af_n[4][q] = (bf16_t)0.f;
            }
        }

        // ---- epilogue: merged atomics over sorted dsts ----
        #pragma unroll
        for (int nt = 0; nt < 4; nt++) {
            int col = nt * 16 + l15;
            float bb = b2r[nt];
            float* ap = agg + col;
            int dcur = d4.x;
            float v = oa[nt][0] + bb;
            if (d4.y == dcur) v += oa[nt][1] + bb;
            else { atomicAdd(ap + (size_t)dcur * 64, v); dcur = d4.y; v = oa[nt][1] + bb; }
            if (d4.z == dcur) v += oa[nt][2] + bb;
            else { atomicAdd(ap + (size_t)dcur * 64, v); dcur = d4.z; v = oa[nt][2] + bb; }
            if (d4.w == dcur) v += oa[nt][3] + bb;
            else { atomicAdd(ap + (size_t)dcur * 64, v); dcur = d4.w; v = oa[nt][3] + bb; }
            atomicAdd(ap + (size_t)dcur * 64, v);
        }

        if (ntile >= NTILE) break;
        tile = ntile;
        #pragma unroll
        for (int i = 0; i < 5; i++) af[i] = af_n[i];
        d4 = d4_n;
    }
}

// ---------------------------------------------------------------------------
// GRU (MFMA): 64 nodes/block, 16/wave. Emits fp32 h and bf16 hb.
// ---------------------------------------------------------------------------
__global__ __launch_bounds__(256) void gru_kernel(
    const float* __restrict__ agg, const float* __restrict__ h_in,
    float* __restrict__ h_out, bf16_t* __restrict__ hb_out,
    const bf16_t* __restrict__ Wxt, const bf16_t* __restrict__ Wht,
    const float* __restrict__ bg)
{
    __shared__ __attribute__((aligned(16))) float shd[64 * 68];   // 17408 B
    const int tid = threadIdx.x;
    const int n0  = blockIdx.x * 64;

    for (int idx = tid; idx < 64 * 16; idx += 256) {
        int i = idx >> 4, c = (idx & 15) * 4;
        int n = n0 + i; if (n >= NN) n = NN - 1;
        *(float4*)&shd[i * 68 + c] = *(const float4*)(h_in + (size_t)n * 64 + c);
    }
    __syncthreads();

    const int lane = tid & 63;
    const int wv   = tid >> 6;
    const int l15  = lane & 15;
    const int quad = lane >> 4;
    const int rowA = wv * 16 + l15;
    int nA = n0 + rowA; if (nA >= NN) nA = NN - 1;

    bf16x8 ax[2], ah[2];
    ax[0] = cvt8(agg + (size_t)nA * 64 + quad * 8);
    ax[1] = cvt8(agg + (size_t)nA * 64 + quad * 8 + 32);
    {
        const float* hp = shd + rowA * 68 + quad * 8;
        ah[0] = cvt8(hp);
        ah[1] = cvt8(hp + 32);
    }

    floatx4 az[4], ar[4], axh[4], ahh[4];
    #pragma unroll
    for (int nt = 0; nt < 4; nt++) {
        az[nt].x=0.f; az[nt].y=0.f; az[nt].z=0.f; az[nt].w=0.f;
        ar[nt].x=0.f; ar[nt].y=0.f; ar[nt].z=0.f; ar[nt].w=0.f;
        axh[nt].x=0.f; axh[nt].y=0.f; axh[nt].z=0.f; axh[nt].w=0.f;
        ahh[nt].x=0.f; ahh[nt].y=0.f; ahh[nt].z=0.f; ahh[nt].w=0.f;
    }
    #pragma unroll
    for (int nt = 0; nt < 4; nt++) {
        const bf16_t* bx_z = Wxt + (nt * 16 + l15) * 64 + quad * 8;
        const bf16_t* bh_z = Wht + (nt * 16 + l15) * 64 + quad * 8;
        const bf16_t* bx_r = bx_z + 64 * 64;
        const bf16_t* bh_r = bh_z + 64 * 64;
        const bf16_t* bx_h = bx_z + 128 * 64;
        const bf16_t* bh_h = bh_z + 128 * 64;
        az[nt]  = mfma16(ax[0], *(const bf16x8*)bx_z,        az[nt]);
        az[nt]  = mfma16(ax[1], *(const bf16x8*)(bx_z + 32), az[nt]);
        az[nt]  = mfma16(ah[0], *(const bf16x8*)bh_z,        az[nt]);
        az[nt]  = mfma16(ah[1], *(const bf16x8*)(bh_z + 32), az[nt]);
        ar[nt]  = mfma16(ax[0], *(const bf16x8*)bx_r,        ar[nt]);
        ar[nt]  = mfma16(ax[1], *(const bf16x8*)(bx_r + 32), ar[nt]);
        ar[nt]  = mfma16(ah[0], *(const bf16x8*)bh_r,        ar[nt]);
        ar[nt]  = mfma16(ah[1], *(const bf16x8*)(bh_r + 32), ar[nt]);
        axh[nt] = mfma16(ax[0], *(const bf16x8*)bx_h,        axh[nt]);
        axh[nt] = mfma16(ax[1], *(const bf16x8*)(bx_h + 32), axh[nt]);
        ahh[nt] = mfma16(ah[0], *(const bf16x8*)bh_h,        ahh[nt]);
        ahh[nt] = mfma16(ah[1], *(const bf16x8*)(bh_h + 32), ahh[nt]);
    }

    #pragma unroll
    for (int nt = 0; nt < 4; nt++) {
        int j = nt * 16 + l15;
        float bz = bg[j], brr = bg[64 + j], bh = bg[128 + j];
        #pragma unroll
        for (int r = 0; r < 4; r++) {
            int lrow = wv * 16 + quad * 4 + r;
            int n = n0 + lrow;
            float z  = sigm_f(az[nt][r] + bz);
            float rr = sigm_f(ar[nt][r] + brr);
            float hc = tanh_f(axh[nt][r] + bh + rr * ahh[nt][r]);
            float hold = shd[lrow * 68 + j];
            float hnew = z * hold + (1.f - z) * hc;
            if (n < NN) {
                h_out[(size_t)n * 64 + j]  = hnew;
                hb_out[(size_t)n * 64 + j] = (bf16_t)hnew;
            }
        }
    }
}

// ---------------------------------------------------------------------------
// readout (unchanged; unroll-1 pinned against the R1 spill).
// ---------------------------------------------------------------------------
__global__ __launch_bounds__(256) void readout_kernel(
    const float* __restrict__ h, const float* __restrict__ Wr1,
    const float* __restrict__ br1, const float* __restrict__ Wr2,
    const float* __restrict__ br2, float* __restrict__ out)
{
    __shared__ float shd[32][64];
    const int tid = threadIdx.x;
    const int nb0 = blockIdx.x * 32;

    for (int idx = tid; idx < 32 * 16; idx += 256) {
        int i = idx >> 4, c = (idx & 15) * 4;
        int n = nb0 + i;
        float4 hv = make_float4(0.f, 0.f, 0.f, 0.f);
        if (n < NN) hv = *(const float4*)(h + (size_t)n * 64 + c);
        *(float4*)&shd[i][c] = hv;
    }
    __syncthreads();

    const int j  = tid & 63;
    const int wv = tid >> 6;

    float c0[8], c1[8];
    #pragma unroll
    for (int ii = 0; ii < 8; ii++) { c0[ii] = 0.f; c1[ii] = 0.f; }

    #pragma unroll 1
    for (int k0 = 0; k0 < 64; k0 += 2) {
        float2 h2[8];
        #pragma unroll
        for (int ii = 0; ii < 8; ii++) h2[ii] = *(const float2*)&shd[wv * 8 + ii][k0];
        #pragma unroll
        for (int kk = 0; kk < 2; kk++) {
            int k = k0 + kk;
            float w0 = Wr1[k * 128 + j];
            float w1 = Wr1[k * 128 + 64 + j];
            #pragma unroll
            for (int ii = 0; ii < 8; ii++) {
                float hv = kk ? h2[ii].y : h2[ii].x;
                c0[ii] = fmaf(hv, w0, c0[ii]);
                c1[ii] = fmaf(hv, w1, c1[ii]);
            }
        }
    }

    float r2a = Wr2[j], r2b = Wr2[64 + j];
    float bb0 = br1[j], bb1 = br1[64 + j];
    float br2v = br2[0];
    #pragma unroll
    for (int ii = 0; ii < 8; ii++) {
        float p = fmaxf(c0[ii] + bb0, 0.f) * r2a + fmaxf(c1[ii] + bb1, 0.f) * r2b;
        #pragma unroll
        for (int m = 32; m >= 1; m >>= 1) p += __shfl_xor(p, m, 64);
        if (j == 0) {
            int n = nb0 + wv * 8 + ii;
            if (n < NN) out[n] = p + br2v;
        }
    }
}

// ---------------------------------------------------------------------------
extern "C" void kernel_launch(void* const* d_in, const int* in_sizes, int n_in,
                              void* d_out, int out_size, void* d_ws, size_t ws_size,
                              hipStream_t stream)
{
    const float* nf  = (const float*)d_in[0];
    const float* ef  = (const float*)d_in[1];
    const int* esrc  = (const int*)d_in[2];
    const int* edst  = (const int*)d_in[3];
    const float* Wm1 = (const float*)d_in[4];
    const float* bm1 = (const float*)d_in[5];
    const float* Wm2 = (const float*)d_in[6];
    const float* bm2 = (const float*)d_in[7];
    const float* Wx  = (const float*)d_in[8];
    const float* Wh  = (const float*)d_in[9];
    const float* bg  = (const float*)d_in[10];
    const float* Wr1 = (const float*)d_in[11];
    const float* br1 = (const float*)d_in[12];
    const float* Wr2 = (const float*)d_in[13];
    const float* br2 = (const float*)d_in[14];

    char* ws = (char*)d_ws;
    float*  hbuf   = (float*)(ws);                   // 12,800,000
    float*  agg    = (float*)(ws + 12800000);        // 12,800,000
    bf16_t* hb     = (bf16_t*)(ws + 25600000);       // 6,400,000
    bf16_t* W1f    = (bf16_t*)(ws + 32000000);       // 40,960
    bf16_t* W2f    = (bf16_t*)(ws + 32040960);       // 16,384
    bf16_t* Wxt    = (bf16_t*)(ws + 32057344);       // 24,576
    bf16_t* Wht    = (bf16_t*)(ws + 32081920);       // 24,576
    int*    srcs   = (int*)(ws + 32106496);          // 1,600,000
    int*    dsts   = (int*)(ws + 33706496);          // 1,600,000
    bf16_t* efpb   = (bf16_t*)(ws + 35306496);       // 6,400,000
    int*    deg    = (int*)(ws + 41706496);          // 200,704
    int*    cursor = (int*)(ws + 41907200);          // 200,704
    int*    chunkS = (int*)(ws + 42107904);          // 1,024
    int*    chunkO = (int*)(ws + 42108928);          // 1,024

    prep_kernel<<<208, 256, 0, stream>>>(Wm1, Wm2, Wx, Wh, W1f, W2f, Wxt, Wht);
    hb0_kernel<<<3125, 256, 0, stream>>>(nf, hb);

    // CSR build (same work every call)
    hipMemsetAsync(deg, 0, NPAD * 4, stream);
    hist_kernel<<<(NE + 255) / 256, 256, 0, stream>>>(edst, deg);
    scanA_kernel<<<NCH, 256, 0, stream>>>(deg, chunkS);
    scanB_kernel<<<1, 256, 0, stream>>>(chunkS, chunkO);
    scanC_kernel<<<NCH, 256, 0, stream>>>(deg, chunkO, cursor);
    scatter_kernel<<<(NE + 255) / 256, 256, 0, stream>>>(esrc, edst, ef, cursor,
                                                         srcs, dsts, efpb);

    for (int t = 0; t < 2; t++) {
        const float* h_in = (t == 0) ? nf : hbuf;
        hipMemsetAsync(agg, 0, (size_t)NN * 64 * 4, stream);
        edge_kernel<<<512, 256, 0, stream>>>(hb, efpb, srcs, dsts,
                                             W1f, W2f, bm1, bm2, agg);
        gru_kernel<<<(NN + 63) / 64, 256, 0, stream>>>(agg, h_in, hbuf, hb,
                                                       Wxt, Wht, bg);
    }
    readout_kernel<<<(NN + 31) / 32, 256, 0, stream>>>(hbuf, Wr1, br1, Wr2, br2,
                                                       (float*)d_out);
}

// Round 9
// 360.009 us; speedup vs baseline: 1.9096x; 1.0720x over previous
//
#include <hip/hip_runtime.h>
#include <hip/hip_bf16.h>

#define NN 50000
#define NE 400000
#define NGRP 25000         // NE/16 wave-groups
#define NCH 196            // ceil(50176/256) scan chunks
#define NPAD 50176         // NCH*256

typedef __bf16 bf16_t;
typedef __bf16 bf16x4 __attribute__((ext_vector_type(4)));
typedef __bf16 bf16x8 __attribute__((ext_vector_type(8)));
typedef float  floatx4 __attribute__((ext_vector_type(4)));

static __device__ __forceinline__ floatx4 mfma16(bf16x8 a, bf16x8 b, floatx4 c) {
    return __builtin_amdgcn_mfma_f32_16x16x32_bf16(a, b, c, 0, 0, 0);
}
static __device__ __forceinline__ float sigm_f(float x) {
    return 1.f / (1.f + __expf(-x));
}
static __device__ __forceinline__ float tanh_f(float x) {
    return 1.f - 2.f / (__expf(2.f * x) + 1.f);
}
static __device__ __forceinline__ bf16x8 cvt8(const float* sp) {
    float4 f0 = *(const float4*)sp;
    float4 f1 = *(const float4*)(sp + 4);
    bf16x8 v;
    v[0] = (bf16_t)f0.x; v[1] = (bf16_t)f0.y; v[2] = (bf16_t)f0.z; v[3] = (bf16_t)f0.w;
    v[4] = (bf16_t)f1.x; v[5] = (bf16_t)f1.y; v[6] = (bf16_t)f1.z; v[7] = (bf16_t)f1.w;
    return v;
}

// ---------------------------------------------------------------------------
// prep (fused with hb0): bf16 h copy + all weight transforms into
// MFMA-fragment-linear order.
// W1f: [8 nt][5 ks][64 lane][8 j]   (k-pad 136->160)
// W2f: [4 nt][4 kg][64 lane][8 j]
// Wr1f:[8 nt][2 kg][64 lane][8 j]   (readout hidden layer)
// Wxt/Wht: [n][k] transposed bf16 for the GRU.
// ---------------------------------------------------------------------------
__global__ __launch_bounds__(256) void prep_kernel(
    const float* __restrict__ nf,
    const float* __restrict__ Wm1, const float* __restrict__ Wm2,
    const float* __restrict__ Wx,  const float* __restrict__ Wh,
    const float* __restrict__ Wr1,
    bf16_t* __restrict__ hb,
    bf16_t* __restrict__ W1f, bf16_t* __restrict__ W2f,
    bf16_t* __restrict__ Wxt, bf16_t* __restrict__ Wht,
    bf16_t* __restrict__ Wr1f)
{
    int u = blockIdx.x * 256 + threadIdx.x;
    if (u < 800000) {          // hb: 4 elems per thread
        float4 v = *(const float4*)(nf + (size_t)u * 4);
        bf16x4 o;
        o[0] = (bf16_t)v.x; o[1] = (bf16_t)v.y; o[2] = (bf16_t)v.z; o[3] = (bf16_t)v.w;
        *(bf16x4*)(hb + (size_t)u * 4) = o;
        return;
    }
    u -= 800000;
    if (u < 20480) {
        int j = u & 7, l = (u >> 3) & 63, rem = u >> 9;   // rem 0..39
        int ks = rem % 5, nt = rem / 5;
        int n = nt * 16 + (l & 15);
        int k = ks * 32 + (l >> 4) * 8 + j;
        W1f[u] = (k < 136) ? (bf16_t)Wm1[k * 128 + n] : (bf16_t)0.f;
        return;
    }
    u -= 20480;
    if (u < 8192) {
        int j = u & 7, l = (u >> 3) & 63, rem = u >> 9;   // rem 0..15
        int kg = rem & 3, nt = rem >> 2;
        int n = nt * 16 + (l & 15);
        int k = kg * 32 + (l >> 4) * 8 + j;
        W2f[u] = (bf16_t)Wm2[k * 64 + n];
        return;
    }
    u -= 8192;
    if (u < 12288) {
        int n = u >> 6, k = u & 63;
        Wxt[u] = (bf16_t)Wx[k * 192 + n];
        return;
    }
    u -= 12288;
    if (u < 12288) {
        int n = u >> 6, k = u & 63;
        Wht[u] = (bf16_t)Wh[k * 192 + n];
        return;
    }
    u -= 12288;
    if (u < 8192) {            // Wr1f: [64][128] -> frag-linear
        int j = u & 7, l = (u >> 3) & 63, rem = u >> 9;   // rem 0..15
        int kg = rem & 1, nt = rem >> 1;
        int n = nt * 16 + (l & 15);
        int k = kg * 32 + (l >> 4) * 8 + j;
        Wr1f[u] = (bf16_t)Wr1[k * 128 + n];
    }
}

// ---------------------------------------------------------------------------
// CSR build: hist -> scan -> scatter (permute srcs/dsts/ef->bf16, dst-sorted)
// ---------------------------------------------------------------------------
__global__ __launch_bounds__(256) void hist_kernel(
    const int* __restrict__ edst, int* __restrict__ deg)
{
    int e = blockIdx.x * 256 + threadIdx.x;
    if (e < NE) atomicAdd(&deg[edst[e]], 1);
}

__global__ __launch_bounds__(256) void scanA_kernel(
    const int* __restrict__ deg, int* __restrict__ chunkSums)
{
    __shared__ int s[256];
    int i = blockIdx.x * 256 + threadIdx.x;
    s[threadIdx.x] = deg[i];
    __syncthreads();
    for (int st = 128; st >= 1; st >>= 1) {
        if (threadIdx.x < st) s[threadIdx.x] += s[threadIdx.x + st];
        __syncthreads();
    }
    if (threadIdx.x == 0) chunkSums[blockIdx.x] = s[0];
}

__global__ __launch_bounds__(256) void scanB_kernel(
    const int* __restrict__ chunkSums, int* __restrict__ chunkOff)
{
    __shared__ int s[256];
    int t = threadIdx.x;
    int v = (t < NCH) ? chunkSums[t] : 0;
    s[t] = v;
    __syncthreads();
    for (int st = 1; st < 256; st <<= 1) {
        int add = (t >= st) ? s[t - st] : 0;
        __syncthreads();
        s[t] += add;
        __syncthreads();
    }
    if (t < NCH) chunkOff[t] = s[t] - v;   // exclusive
}

__global__ __launch_bounds__(256) void scanC_kernel(
    const int* __restrict__ deg, const int* __restrict__ chunkOff,
    int* __restrict__ cursor)
{
    __shared__ int s[256];
    int t = threadIdx.x;
    int i = blockIdx.x * 256 + t;
    int v = deg[i];
    s[t] = v;
    __syncthreads();
    for (int st = 1; st < 256; st <<= 1) {
        int add = (t >= st) ? s[t - st] : 0;
        __syncthreads();
        s[t] += add;
        __syncthreads();
    }
    cursor[i] = chunkOff[blockIdx.x] + s[t] - v;   // exclusive
}

__global__ __launch_bounds__(256) void scatter_kernel(
    const int* __restrict__ esrc, const int* __restrict__ edst,
    const float* __restrict__ ef,
    int* __restrict__ cursor, int* __restrict__ srcs, int* __restrict__ dsts,
    bf16_t* __restrict__ efpb)
{
    int e = blockIdx.x * 256 + threadIdx.x;
    if (e >= NE) return;
    int d = edst[e];
    int p = atomicAdd(&cursor[d], 1);
    srcs[p] = esrc[e];
    dsts[p] = d;
    float4 a = *(const float4*)(ef + (size_t)e * 8);
    float4 b = *(const float4*)(ef + (size_t)e * 8 + 4);
    bf16x8 v;
    v[0] = (bf16_t)a.x; v[1] = (bf16_t)a.y; v[2] = (bf16_t)a.z; v[3] = (bf16_t)a.w;
    v[4] = (bf16_t)b.x; v[5] = (bf16_t)b.y; v[6] = (bf16_t)b.z; v[7] = (bf16_t)b.w;
    *(bf16x8*)(efpb + (size_t)p * 8) = v;
}

// ---------------------------------------------------------------------------
// edge kernel v9: 512-thread blocks, DEFAULT bounds (R7 lesson: a tight
// bounds cap spills register arrays -> scratch storm). 8 waves share one
// frag-linear W1+W2 LDS copy: 66.6KB -> 2 blocks/CU = 16 waves/CU (R8 had 8,
// Occupancy 18.6% and MfmaUtil 12.5% -> latency-bound; this doubles overlap).
// Per-wave independent 16-edge groups, software-pipelined gather: next
// group's A-frags issued BEFORE this group's atomics so the atomic retire
// stays out of the next iteration's vmcnt chain.
// ---------------------------------------------------------------------------
__global__ __launch_bounds__(512) void edge_kernel(
    const bf16_t* __restrict__ hb, const bf16_t* __restrict__ efpb,
    const int* __restrict__ srcs, const int* __restrict__ dsts,
    const bf16_t* __restrict__ W1f, const bf16_t* __restrict__ W2f,
    const float* __restrict__ b1f, const float* __restrict__ b2f,
    float* __restrict__ agg)
{
    __shared__ __attribute__((aligned(16))) bf16_t w1s[20480];     // 40960 B
    __shared__ __attribute__((aligned(16))) bf16_t w2s[8192];      // 16384 B
    __shared__ __attribute__((aligned(16))) bf16_t hq[8][16 * 36]; //  9216 B

    const int tid = threadIdx.x;
    {
        const uint4* s1 = (const uint4*)W1f;
        uint4* d1 = (uint4*)w1s;
        #pragma unroll
        for (int i = 0; i < 5; i++) d1[tid + i * 512] = s1[tid + i * 512];
        const uint4* s2 = (const uint4*)W2f;
        uint4* d2 = (uint4*)w2s;
        #pragma unroll
        for (int i = 0; i < 2; i++) d2[tid + i * 512] = s2[tid + i * 512];
    }
    __syncthreads();

    const int lane = tid & 63;
    const int wv   = tid >> 6;      // 0..7
    const int l15  = lane & 15;
    const int quad = lane >> 4;

    float b1r[8], b2r[4];
    #pragma unroll
    for (int nt = 0; nt < 8; nt++) b1r[nt] = b1f[nt * 16 + l15];
    #pragma unroll
    for (int nt = 0; nt < 4; nt++) b2r[nt] = b2f[nt * 16 + l15];

    const int WTOT = gridDim.x * 8;
    int g = blockIdx.x * 8 + wv;

    // prefetch group-0 operands
    bf16x8 af[5];
    int4 d4;
    {
        int row = g * 16 + l15;
        int si = srcs[row], di = dsts[row];
        const bf16_t* sp = hb + (size_t)si * 64 + quad * 8;
        const bf16_t* dp = hb + (size_t)di * 64 + quad * 8;
        af[0] = *(const bf16x8*)sp;  af[1] = *(const bf16x8*)(sp + 32);
        af[2] = *(const bf16x8*)dp;  af[3] = *(const bf16x8*)(dp + 32);
        if (quad == 0) {
            af[4] = *(const bf16x8*)(efpb + (size_t)row * 8);
        } else {
            #pragma unroll
            for (int q = 0; q < 8; q++) af[4][q] = (bf16_t)0.f;
        }
        d4 = *(const int4*)(dsts + g * 16 + quad * 4);
    }

    while (true) {
        int gn = g + WTOT;
        int gp = (gn < NGRP) ? gn : g;            // clamped, in-bounds
        int prow = gp * 16 + l15;
        int si_n = srcs[prow], di_n = dsts[prow];
        int4 d4_n = *(const int4*)(dsts + gp * 16 + quad * 4);

        // ---- GEMM1/GEMM2 in four 32-col quarters ----
        floatx4 oa[4];
        #pragma unroll
        for (int nt = 0; nt < 4; nt++) { oa[nt].x = 0.f; oa[nt].y = 0.f; oa[nt].z = 0.f; oa[nt].w = 0.f; }

        #pragma unroll
        for (int q = 0; q < 4; q++) {
            floatx4 acc[2];
            #pragma unroll
            for (int nt = 0; nt < 2; nt++) { acc[nt].x = 0.f; acc[nt].y = 0.f; acc[nt].z = 0.f; acc[nt].w = 0.f; }
            #pragma unroll
            for (int nt = 0; nt < 2; nt++) {
                int gnt = q * 2 + nt;
                #pragma unroll
                for (int ks = 0; ks < 5; ks++) {
                    bf16x8 b = *(const bf16x8*)(w1s + ((gnt * 5 + ks) * 64 + lane) * 8);
                    acc[nt] = mfma16(af[ks], b, acc[nt]);
                }
            }
            #pragma unroll
            for (int nt = 0; nt < 2; nt++) {
                float bb = b1r[q * 2 + nt];
                #pragma unroll
                for (int r = 0; r < 4; r++) {
                    float v = fmaxf(acc[nt][r] + bb, 0.f);
                    hq[wv][(quad * 4 + r) * 36 + nt * 16 + l15] = (bf16_t)v;
                }
            }
            // same-wave write->read (compiler lgkmcnt)
            bf16x8 hf = *(const bf16x8*)(hq[wv] + l15 * 36 + quad * 8);
            #pragma unroll
            for (int nt = 0; nt < 4; nt++) {
                bf16x8 w2 = *(const bf16x8*)(w2s + ((nt * 4 + q) * 64 + lane) * 8);
                oa[nt] = mfma16(hf, w2, oa[nt]);
            }
        }

        // ---- prefetch next-group A fragments BEFORE atomics ----
        bf16x8 af_n[5];
        {
            const bf16_t* sp = hb + (size_t)si_n * 64 + quad * 8;
            const bf16_t* dp = hb + (size_t)di_n * 64 + quad * 8;
            af_n[0] = *(const bf16x8*)sp;  af_n[1] = *(const bf16x8*)(sp + 32);
            af_n[2] = *(const bf16x8*)dp;  af_n[3] = *(const bf16x8*)(dp + 32);
            if (quad == 0) {
                af_n[4] = *(const bf16x8*)(efpb + (size_t)prow * 8);
            } else {
                #pragma unroll
                for (int q = 0; q < 8; q++) af_n[4][q] = (bf16_t)0.f;
            }
        }

        // ---- epilogue: merged atomics over sorted dsts ----
        #pragma unroll
        for (int nt = 0; nt < 4; nt++) {
            int col = nt * 16 + l15;
            float bb = b2r[nt];
            float* ap = agg + col;
            int dcur = d4.x;
            float v = oa[nt][0] + bb;
            if (d4.y == dcur) v += oa[nt][1] + bb;
            else { atomicAdd(ap + (size_t)dcur * 64, v); dcur = d4.y; v = oa[nt][1] + bb; }
            if (d4.z == dcur) v += oa[nt][2] + bb;
            else { atomicAdd(ap + (size_t)dcur * 64, v); dcur = d4.z; v = oa[nt][2] + bb; }
            if (d4.w == dcur) v += oa[nt][3] + bb;
            else { atomicAdd(ap + (size_t)dcur * 64, v); dcur = d4.w; v = oa[nt][3] + bb; }
            atomicAdd(ap + (size_t)dcur * 64, v);
        }

        if (gn >= NGRP) break;
        g = gn;
        #pragma unroll
        for (int i = 0; i < 5; i++) af[i] = af_n[i];
        d4 = d4_n;
    }
}

// ---------------------------------------------------------------------------
// GRU (MFMA): 64 nodes/block, 16/wave. LAST=0: emits fp32 h + bf16 hb.
// LAST=1: fuses the readout MLP (hnew -> per-wave bf16 LDS tile -> A-frags
// -> x Wr1f (16 MFMA) -> relu dot Wr2 -> quad shuffle-reduce -> out).
// ---------------------------------------------------------------------------
template<int LAST>
__global__ __launch_bounds__(256) void gru_kernel(
    const float* __restrict__ agg, const float* __restrict__ h_in,
    float* __restrict__ h_out, bf16_t* __restrict__ hb_out,
    const bf16_t* __restrict__ Wxt, const bf16_t* __restrict__ Wht,
    const float* __restrict__ bg,
    const bf16_t* __restrict__ Wr1f, const float* __restrict__ br1,
    const float* __restrict__ Wr2, const float* __restrict__ br2,
    float* __restrict__ out)
{
    __shared__ __attribute__((aligned(16))) float  shd[64 * 68];   // 17408 B
    __shared__ __attribute__((aligned(16))) bf16_t hb2[4][16 * 72]; // 9216 B
    const int tid = threadIdx.x;
    const int n0  = blockIdx.x * 64;

    for (int idx = tid; idx < 64 * 16; idx += 256) {
        int i = idx >> 4, c = (idx & 15) * 4;
        int n = n0 + i; if (n >= NN) n = NN - 1;
        *(float4*)&shd[i * 68 + c] = *(const float4*)(h_in + (size_t)n * 64 + c);
    }
    __syncthreads();

    const int lane = tid & 63;
    const int wv   = tid >> 6;
    const int l15  = lane & 15;
    const int quad = lane >> 4;
    const int rowA = wv * 16 + l15;
    int nA = n0 + rowA; if (nA >= NN) nA = NN - 1;

    bf16x8 ax[2], ah[2];
    ax[0] = cvt8(agg + (size_t)nA * 64 + quad * 8);
    ax[1] = cvt8(agg + (size_t)nA * 64 + quad * 8 + 32);
    {
        const float* hp = shd + rowA * 68 + quad * 8;
        ah[0] = cvt8(hp);
        ah[1] = cvt8(hp + 32);
    }

    floatx4 az[4], ar[4], axh[4], ahh[4];
    #pragma unroll
    for (int nt = 0; nt < 4; nt++) {
        az[nt].x=0.f; az[nt].y=0.f; az[nt].z=0.f; az[nt].w=0.f;
        ar[nt].x=0.f; ar[nt].y=0.f; ar[nt].z=0.f; ar[nt].w=0.f;
        axh[nt].x=0.f; axh[nt].y=0.f; axh[nt].z=0.f; axh[nt].w=0.f;
        ahh[nt].x=0.f; ahh[nt].y=0.f; ahh[nt].z=0.f; ahh[nt].w=0.f;
    }
    #pragma unroll
    for (int nt = 0; nt < 4; nt++) {
        const bf16_t* bx_z = Wxt + (nt * 16 + l15) * 64 + quad * 8;
        const bf16_t* bh_z = Wht + (nt * 16 + l15) * 64 + quad * 8;
        const bf16_t* bx_r = bx_z + 64 * 64;
        const bf16_t* bh_r = bh_z + 64 * 64;
        const bf16_t* bx_h = bx_z + 128 * 64;
        const bf16_t* bh_h = bh_z + 128 * 64;
        az[nt]  = mfma16(ax[0], *(const bf16x8*)bx_z,        az[nt]);
        az[nt]  = mfma16(ax[1], *(const bf16x8*)(bx_z + 32), az[nt]);
        az[nt]  = mfma16(ah[0], *(const bf16x8*)bh_z,        az[nt]);
        az[nt]  = mfma16(ah[1], *(const bf16x8*)(bh_z + 32), az[nt]);
        ar[nt]  = mfma16(ax[0], *(const bf16x8*)bx_r,        ar[nt]);
        ar[nt]  = mfma16(ax[1], *(const bf16x8*)(bx_r + 32), ar[nt]);
        ar[nt]  = mfma16(ah[0], *(const bf16x8*)bh_r,        ar[nt]);
        ar[nt]  = mfma16(ah[1], *(const bf16x8*)(bh_r + 32), ar[nt]);
        axh[nt] = mfma16(ax[0], *(const bf16x8*)bx_h,        axh[nt]);
        axh[nt] = mfma16(ax[1], *(const bf16x8*)(bx_h + 32), axh[nt]);
        ahh[nt] = mfma16(ah[0], *(const bf16x8*)bh_h,        ahh[nt]);
        ahh[nt] = mfma16(ah[1], *(const bf16x8*)(bh_h + 32), ahh[nt]);
    }

    #pragma unroll
    for (int nt = 0; nt < 4; nt++) {
        int j = nt * 16 + l15;
        float bz = bg[j], brr = bg[64 + j], bh = bg[128 + j];
        #pragma unroll
        for (int r = 0; r < 4; r++) {
            int lrow = wv * 16 + quad * 4 + r;
            int n = n0 + lrow;
            float z  = sigm_f(az[nt][r] + bz);
            float rr = sigm_f(ar[nt][r] + brr);
            float hc = tanh_f(axh[nt][r] + bh + rr * ahh[nt][r]);
            float hold = shd[lrow * 68 + j];
            float hnew = z * hold + (1.f - z) * hc;
            if (LAST) {
                hb2[wv][(quad * 4 + r) * 72 + j] = (bf16_t)hnew;
            } else if (n < NN) {
                h_out[(size_t)n * 64 + j]  = hnew;
                hb_out[(size_t)n * 64 + j] = (bf16_t)hnew;
            }
        }
    }

    if (LAST) {
        // readout: hid = relu(hnew @ Wr1 + br1); out = hid @ Wr2 + br2
        // A-frags from per-wave hb2 tile (same-wave write->read, lgkmcnt)
        bf16x8 a0 = *(const bf16x8*)(hb2[wv] + l15 * 72 + quad * 8);
        bf16x8 a1 = *(const bf16x8*)(hb2[wv] + l15 * 72 + quad * 8 + 32);
        floatx4 accR[8];
        #pragma unroll
        for (int nt = 0; nt < 8; nt++) { accR[nt].x=0.f; accR[nt].y=0.f; accR[nt].z=0.f; accR[nt].w=0.f; }
        #pragma unroll
        for (int nt = 0; nt < 8; nt++) {
            bf16x8 b0 = *(const bf16x8*)(Wr1f + ((nt * 2 + 0) * 64 + lane) * 8);
            bf16x8 b1 = *(const bf16x8*)(Wr1f + ((nt * 2 + 1) * 64 + lane) * 8);
            accR[nt] = mfma16(a0, b0, accR[nt]);
            accR[nt] = mfma16(a1, b1, accR[nt]);
        }
        float br1r[8], wr2r[8];
        #pragma unroll
        for (int nt = 0; nt < 8; nt++) {
            br1r[nt] = br1[nt * 16 + l15];
            wr2r[nt] = Wr2[nt * 16 + l15];
        }
        float br2v = br2[0];
        #pragma unroll
        for (int r = 0; r < 4; r++) {
            float p = 0.f;
            #pragma unroll
            for (int nt = 0; nt < 8; nt++)
                p += fmaxf(accR[nt][r] + br1r[nt], 0.f) * wr2r[nt];
            // reduce across the 16 lanes of this quad (xor stays in-group)
            p += __shfl_xor(p, 1, 64);
            p += __shfl_xor(p, 2, 64);
            p += __shfl_xor(p, 4, 64);
            p += __shfl_xor(p, 8, 64);
            if (l15 == 0) {
                int n = n0 + wv * 16 + quad * 4 + r;
                if (n < NN) out[n] = p + br2v;
            }
        }
    }
}

// ---------------------------------------------------------------------------
extern "C" void kernel_launch(void* const* d_in, const int* in_sizes, int n_in,
                              void* d_out, int out_size, void* d_ws, size_t ws_size,
                              hipStream_t stream)
{
    const float* nf  = (const float*)d_in[0];
    const float* ef  = (const float*)d_in[1];
    const int* esrc  = (const int*)d_in[2];
    const int* edst  = (const int*)d_in[3];
    const float* Wm1 = (const float*)d_in[4];
    const float* bm1 = (const float*)d_in[5];
    const float* Wm2 = (const float*)d_in[6];
    const float* bm2 = (const float*)d_in[7];
    const float* Wx  = (const float*)d_in[8];
    const float* Wh  = (const float*)d_in[9];
    const float* bg  = (const float*)d_in[10];
    const float* Wr1 = (const float*)d_in[11];
    const float* br1 = (const float*)d_in[12];
    const float* Wr2 = (const float*)d_in[13];
    const float* br2 = (const float*)d_in[14];

    char* ws = (char*)d_ws;
    float*  hbuf   = (float*)(ws);                   // 12,800,000
    float*  agg    = (float*)(ws + 12800000);        // 12,800,000
    bf16_t* hb     = (bf16_t*)(ws + 25600000);       // 6,400,000
    bf16_t* W1f    = (bf16_t*)(ws + 32000000);       // 40,960
    bf16_t* W2f    = (bf16_t*)(ws + 32040960);       // 16,384
    bf16_t* Wxt    = (bf16_t*)(ws + 32057344);       // 24,576
    bf16_t* Wht    = (bf16_t*)(ws + 32081920);       // 24,576
    bf16_t* Wr1f   = (bf16_t*)(ws + 32106496);       // 16,384
    int*    srcs   = (int*)(ws + 32122880);          // 1,600,000
    int*    dsts   = (int*)(ws + 33722880);          // 1,600,000
    bf16_t* efpb   = (bf16_t*)(ws + 35322880);       // 6,400,000
    int*    deg    = (int*)(ws + 41722880);          // 200,704
    int*    cursor = (int*)(ws + 41923584);          // 200,704
    int*    chunkS = (int*)(ws + 42124288);          // 1,024
    int*    chunkO = (int*)(ws + 42125312);          // 1,024

    prep_kernel<<<3365, 256, 0, stream>>>(nf, Wm1, Wm2, Wx, Wh, Wr1,
                                          hb, W1f, W2f, Wxt, Wht, Wr1f);

    // CSR build (same work every call)
    hipMemsetAsync(deg, 0, NPAD * 4, stream);
    hist_kernel<<<(NE + 255) / 256, 256, 0, stream>>>(edst, deg);
    scanA_kernel<<<NCH, 256, 0, stream>>>(deg, chunkS);
    scanB_kernel<<<1, 256, 0, stream>>>(chunkS, chunkO);
    scanC_kernel<<<NCH, 256, 0, stream>>>(deg, chunkO, cursor);
    scatter_kernel<<<(NE + 255) / 256, 256, 0, stream>>>(esrc, edst, ef, cursor,
                                                         srcs, dsts, efpb);

    for (int t = 0; t < 2; t++) {
        const float* h_in = (t == 0) ? nf : hbuf;
        hipMemsetAsync(agg, 0, (size_t)NN * 64 * 4, stream);
        edge_kernel<<<512, 512, 0, stream>>>(hb, efpb, srcs, dsts,
                                             W1f, W2f, bm1, bm2, agg);
        if (t == 0) {
            gru_kernel<0><<<(NN + 63) / 64, 256, 0, stream>>>(
                agg, h_in, hbuf, hb, Wxt, Wht, bg,
                Wr1f, br1, Wr2, br2, (float*)d_out);
        } else {
            gru_kernel<1><<<(NN + 63) / 64, 256, 0, stream>>>(
                agg, h_in, nullptr, nullptr, Wxt, Wht, bg,
                Wr1f, br1, Wr2, br2, (float*)d_out);
        }
    }
}

// Round 10
// 356.396 us; speedup vs baseline: 1.9290x; 1.0101x over previous
//
#include <hip/hip_runtime.h>
#include <hip/hip_bf16.h>

#define NN 50000
#define NE 400000
#define NPAIR 12500        // NE/32: 32 sorted edges per wave-iteration
#define NCH 196            // ceil(50176/256) scan chunks
#define NPAD 50176         // NCH*256

typedef __bf16 bf16_t;
typedef __bf16 bf16x4 __attribute__((ext_vector_type(4)));
typedef __bf16 bf16x8 __attribute__((ext_vector_type(8)));
typedef float  floatx4 __attribute__((ext_vector_type(4)));

static __device__ __forceinline__ floatx4 mfma16(bf16x8 a, bf16x8 b, floatx4 c) {
    return __builtin_amdgcn_mfma_f32_16x16x32_bf16(a, b, c, 0, 0, 0);
}
static __device__ __forceinline__ float sigm_f(float x) {
    return 1.f / (1.f + __expf(-x));
}
static __device__ __forceinline__ float tanh_f(float x) {
    return 1.f - 2.f / (__expf(2.f * x) + 1.f);
}
static __device__ __forceinline__ bf16x8 cvt8(const float* sp) {
    float4 f0 = *(const float4*)sp;
    float4 f1 = *(const float4*)(sp + 4);
    bf16x8 v;
    v[0] = (bf16_t)f0.x; v[1] = (bf16_t)f0.y; v[2] = (bf16_t)f0.z; v[3] = (bf16_t)f0.w;
    v[4] = (bf16_t)f1.x; v[5] = (bf16_t)f1.y; v[6] = (bf16_t)f1.z; v[7] = (bf16_t)f1.w;
    return v;
}

// ---------------------------------------------------------------------------
// prep (fused): bf16 h copy + weight transforms into MFMA-fragment-linear.
// W1f: [8 nt][5 ks][64 lane][8 j]   (k-pad 136->160)
// W2f: [4 nt][4 kg][64 lane][8 j]
// Wr1f:[8 nt][2 kg][64 lane][8 j]
// Wxt/Wht: [n][k] transposed bf16 for the GRU.
// ---------------------------------------------------------------------------
__global__ __launch_bounds__(256) void prep_kernel(
    const float* __restrict__ nf,
    const float* __restrict__ Wm1, const float* __restrict__ Wm2,
    const float* __restrict__ Wx,  const float* __restrict__ Wh,
    const float* __restrict__ Wr1,
    bf16_t* __restrict__ hb,
    bf16_t* __restrict__ W1f, bf16_t* __restrict__ W2f,
    bf16_t* __restrict__ Wxt, bf16_t* __restrict__ Wht,
    bf16_t* __restrict__ Wr1f)
{
    int u = blockIdx.x * 256 + threadIdx.x;
    if (u < 800000) {          // hb: 4 elems per thread
        float4 v = *(const float4*)(nf + (size_t)u * 4);
        bf16x4 o;
        o[0] = (bf16_t)v.x; o[1] = (bf16_t)v.y; o[2] = (bf16_t)v.z; o[3] = (bf16_t)v.w;
        *(bf16x4*)(hb + (size_t)u * 4) = o;
        return;
    }
    u -= 800000;
    if (u < 20480) {
        int j = u & 7, l = (u >> 3) & 63, rem = u >> 9;   // rem 0..39
        int ks = rem % 5, nt = rem / 5;
        int n = nt * 16 + (l & 15);
        int k = ks * 32 + (l >> 4) * 8 + j;
        W1f[u] = (k < 136) ? (bf16_t)Wm1[k * 128 + n] : (bf16_t)0.f;
        return;
    }
    u -= 20480;
    if (u < 8192) {
        int j = u & 7, l = (u >> 3) & 63, rem = u >> 9;   // rem 0..15
        int kg = rem & 3, nt = rem >> 2;
        int n = nt * 16 + (l & 15);
        int k = kg * 32 + (l >> 4) * 8 + j;
        W2f[u] = (bf16_t)Wm2[k * 64 + n];
        return;
    }
    u -= 8192;
    if (u < 12288) {
        int n = u >> 6, k = u & 63;
        Wxt[u] = (bf16_t)Wx[k * 192 + n];
        return;
    }
    u -= 12288;
    if (u < 12288) {
        int n = u >> 6, k = u & 63;
        Wht[u] = (bf16_t)Wh[k * 192 + n];
        return;
    }
    u -= 12288;
    if (u < 8192) {            // Wr1f
        int j = u & 7, l = (u >> 3) & 63, rem = u >> 9;   // rem 0..15
        int kg = rem & 1, nt = rem >> 1;
        int n = nt * 16 + (l & 15);
        int k = kg * 32 + (l >> 4) * 8 + j;
        Wr1f[u] = (bf16_t)Wr1[k * 128 + n];
    }
}

// ---------------------------------------------------------------------------
// CSR build: hist -> scan -> scatter (permute srcs/dsts/ef->bf16, dst-sorted)
// ---------------------------------------------------------------------------
__global__ __launch_bounds__(256) void hist_kernel(
    const int* __restrict__ edst, int* __restrict__ deg)
{
    int e = blockIdx.x * 256 + threadIdx.x;
    if (e < NE) atomicAdd(&deg[edst[e]], 1);
}

__global__ __launch_bounds__(256) void scanA_kernel(
    const int* __restrict__ deg, int* __restrict__ chunkSums)
{
    __shared__ int s[256];
    int i = blockIdx.x * 256 + threadIdx.x;
    s[threadIdx.x] = deg[i];
    __syncthreads();
    for (int st = 128; st >= 1; st >>= 1) {
        if (threadIdx.x < st) s[threadIdx.x] += s[threadIdx.x + st];
        __syncthreads();
    }
    if (threadIdx.x == 0) chunkSums[blockIdx.x] = s[0];
}

__global__ __launch_bounds__(256) void scanB_kernel(
    const int* __restrict__ chunkSums, int* __restrict__ chunkOff)
{
    __shared__ int s[256];
    int t = threadIdx.x;
    int v = (t < NCH) ? chunkSums[t] : 0;
    s[t] = v;
    __syncthreads();
    for (int st = 1; st < 256; st <<= 1) {
        int add = (t >= st) ? s[t - st] : 0;
        __syncthreads();
        s[t] += add;
        __syncthreads();
    }
    if (t < NCH) chunkOff[t] = s[t] - v;   // exclusive
}

__global__ __launch_bounds__(256) void scanC_kernel(
    const int* __restrict__ deg, const int* __restrict__ chunkOff,
    int* __restrict__ cursor)
{
    __shared__ int s[256];
    int t = threadIdx.x;
    int i = blockIdx.x * 256 + t;
    int v = deg[i];
    s[t] = v;
    __syncthreads();
    for (int st = 1; st < 256; st <<= 1) {
        int add = (t >= st) ? s[t - st] : 0;
        __syncthreads();
        s[t] += add;
        __syncthreads();
    }
    cursor[i] = chunkOff[blockIdx.x] + s[t] - v;   // exclusive
}

__global__ __launch_bounds__(256) void scatter_kernel(
    const int* __restrict__ esrc, const int* __restrict__ edst,
    const float* __restrict__ ef,
    int* __restrict__ cursor, int* __restrict__ srcs, int* __restrict__ dsts,
    bf16_t* __restrict__ efpb)
{
    int e = blockIdx.x * 256 + threadIdx.x;
    if (e >= NE) return;
    int d = edst[e];
    int p = atomicAdd(&cursor[d], 1);
    srcs[p] = esrc[e];
    dsts[p] = d;
    float4 a = *(const float4*)(ef + (size_t)e * 8);
    float4 b = *(const float4*)(ef + (size_t)e * 8 + 4);
    bf16x8 v;
    v[0] = (bf16_t)a.x; v[1] = (bf16_t)a.y; v[2] = (bf16_t)a.z; v[3] = (bf16_t)a.w;
    v[4] = (bf16_t)b.x; v[5] = (bf16_t)b.y; v[6] = (bf16_t)b.z; v[7] = (bf16_t)b.w;
    *(bf16x8*)(efpb + (size_t)p * 8) = v;
}

// ---------------------------------------------------------------------------
// edge kernel v10: 256-thr blocks, 32 sorted edges per wave-iteration (two
// 16-row A-sets share every W1/W2 LDS fragment read -> LDS bytes/edge
// x0.56, iteration overhead/edge x0.5; R9 showed the kernel is bound by a
// shared per-CU resource (occupancy doubling was neutral) and the LDS pipe
// arithmetic fingers the W1 re-read per 16 edges). Frag-linear LDS, no
// register weight arrays, default bounds (R7 lesson). A-prefetch reuses af
// registers and issues BEFORE the epilogue atomics (R8 win).
// ---------------------------------------------------------------------------
__global__ __launch_bounds__(256) void edge_kernel(
    const bf16_t* __restrict__ hb, const bf16_t* __restrict__ efpb,
    const int* __restrict__ srcs, const int* __restrict__ dsts,
    const bf16_t* __restrict__ W1f, const bf16_t* __restrict__ W2f,
    const float* __restrict__ b1f, const float* __restrict__ b2f,
    float* __restrict__ agg)
{
    __shared__ __attribute__((aligned(16))) bf16_t w1s[20480];      // 40960 B
    __shared__ __attribute__((aligned(16))) bf16_t w2s[8192];       // 16384 B
    __shared__ __attribute__((aligned(16))) bf16_t hq[4][32 * 36];  //  9216 B

    const int tid = threadIdx.x;
    {
        const uint4* s1 = (const uint4*)W1f;
        uint4* d1 = (uint4*)w1s;
        #pragma unroll
        for (int i = 0; i < 10; i++) d1[tid + i * 256] = s1[tid + i * 256];
        const uint4* s2 = (const uint4*)W2f;
        uint4* d2 = (uint4*)w2s;
        #pragma unroll
        for (int i = 0; i < 4; i++) d2[tid + i * 256] = s2[tid + i * 256];
    }
    __syncthreads();

    const int lane = tid & 63;
    const int wv   = tid >> 6;
    const int l15  = lane & 15;
    const int quad = lane >> 4;

    float b1r[8], b2r[4];
    #pragma unroll
    for (int nt = 0; nt < 8; nt++) b1r[nt] = b1f[nt * 16 + l15];
    #pragma unroll
    for (int nt = 0; nt < 4; nt++) b2r[nt] = b2f[nt * 16 + l15];

    const int WTOT = gridDim.x * 4;
    int p = blockIdx.x * 4 + wv;           // pair index; grid*4 <= NPAIR

    // gather pair-0 operands
    bf16x8 af0[5], af1[5];
    int4 d40, d41;
    {
        int base = p * 32;
        int r0 = base + l15, r1 = base + 16 + l15;
        int si0 = srcs[r0], di0 = dsts[r0];
        int si1 = srcs[r1], di1 = dsts[r1];
        const bf16_t* sp0 = hb + (size_t)si0 * 64 + quad * 8;
        const bf16_t* dp0 = hb + (size_t)di0 * 64 + quad * 8;
        const bf16_t* sp1 = hb + (size_t)si1 * 64 + quad * 8;
        const bf16_t* dp1 = hb + (size_t)di1 * 64 + quad * 8;
        af0[0] = *(const bf16x8*)sp0;  af0[1] = *(const bf16x8*)(sp0 + 32);
        af0[2] = *(const bf16x8*)dp0;  af0[3] = *(const bf16x8*)(dp0 + 32);
        af1[0] = *(const bf16x8*)sp1;  af1[1] = *(const bf16x8*)(sp1 + 32);
        af1[2] = *(const bf16x8*)dp1;  af1[3] = *(const bf16x8*)(dp1 + 32);
        if (quad == 0) {
            af0[4] = *(const bf16x8*)(efpb + (size_t)r0 * 8);
            af1[4] = *(const bf16x8*)(efpb + (size_t)r1 * 8);
        } else {
            #pragma unroll
            for (int q = 0; q < 8; q++) { af0[4][q] = (bf16_t)0.f; af1[4][q] = (bf16_t)0.f; }
        }
        d40 = *(const int4*)(dsts + base + quad * 4);
        d41 = *(const int4*)(dsts + base + 16 + quad * 4);
    }

    while (true) {
        int pn = p + WTOT;
        int pp = (pn < NPAIR) ? pn : p;    // clamped, in-bounds
        int nbase = pp * 32;
        int nr0 = nbase + l15, nr1 = nbase + 16 + l15;
        int si0n = srcs[nr0], di0n = dsts[nr0];
        int si1n = srcs[nr1], di1n = dsts[nr1];
        int4 d40n = *(const int4*)(dsts + nbase + quad * 4);
        int4 d41n = *(const int4*)(dsts + nbase + 16 + quad * 4);

        floatx4 oa0[4], oa1[4];
        #pragma unroll
        for (int nt = 0; nt < 4; nt++) {
            oa0[nt].x=0.f; oa0[nt].y=0.f; oa0[nt].z=0.f; oa0[nt].w=0.f;
            oa1[nt].x=0.f; oa1[nt].y=0.f; oa1[nt].z=0.f; oa1[nt].w=0.f;
        }

        #pragma unroll
        for (int q = 0; q < 4; q++) {
            floatx4 ac0[2], ac1[2];
            #pragma unroll
            for (int nt = 0; nt < 2; nt++) {
                ac0[nt].x=0.f; ac0[nt].y=0.f; ac0[nt].z=0.f; ac0[nt].w=0.f;
                ac1[nt].x=0.f; ac1[nt].y=0.f; ac1[nt].z=0.f; ac1[nt].w=0.f;
            }
            #pragma unroll
            for (int nt = 0; nt < 2; nt++) {
                int gnt = q * 2 + nt;
                #pragma unroll
                for (int ks = 0; ks < 5; ks++) {
                    bf16x8 b = *(const bf16x8*)(w1s + ((gnt * 5 + ks) * 64 + lane) * 8);
                    ac0[nt] = mfma16(af0[ks], b, ac0[nt]);
                    ac1[nt] = mfma16(af1[ks], b, ac1[nt]);
                }
            }
            #pragma unroll
            for (int nt = 0; nt < 2; nt++) {
                float bb = b1r[q * 2 + nt];
                #pragma unroll
                for (int r = 0; r < 4; r++) {
                    float v0 = fmaxf(ac0[nt][r] + bb, 0.f);
                    float v1 = fmaxf(ac1[nt][r] + bb, 0.f);
                    hq[wv][(quad * 4 + r) * 36 + nt * 16 + l15]        = (bf16_t)v0;
                    hq[wv][(16 + quad * 4 + r) * 36 + nt * 16 + l15]   = (bf16_t)v1;
                }
            }
            // same-wave write->read (compiler lgkmcnt)
            bf16x8 hf0 = *(const bf16x8*)(hq[wv] + l15 * 36 + quad * 8);
            bf16x8 hf1 = *(const bf16x8*)(hq[wv] + (16 + l15) * 36 + quad * 8);
            #pragma unroll
            for (int nt = 0; nt < 4; nt++) {
                bf16x8 w2 = *(const bf16x8*)(w2s + ((nt * 4 + q) * 64 + lane) * 8);
                oa0[nt] = mfma16(hf0, w2, oa0[nt]);
                oa1[nt] = mfma16(hf1, w2, oa1[nt]);
            }
        }

        // ---- prefetch next-pair A fragments BEFORE atomics (reuse af regs)
        {
            const bf16_t* sp0 = hb + (size_t)si0n * 64 + quad * 8;
            const bf16_t* dp0 = hb + (size_t)di0n * 64 + quad * 8;
            const bf16_t* sp1 = hb + (size_t)si1n * 64 + quad * 8;
            const bf16_t* dp1 = hb + (size_t)di1n * 64 + quad * 8;
            af0[0] = *(const bf16x8*)sp0;  af0[1] = *(const bf16x8*)(sp0 + 32);
            af0[2] = *(const bf16x8*)dp0;  af0[3] = *(const bf16x8*)(dp0 + 32);
            af1[0] = *(const bf16x8*)sp1;  af1[1] = *(const bf16x8*)(sp1 + 32);
            af1[2] = *(const bf16x8*)dp1;  af1[3] = *(const bf16x8*)(dp1 + 32);
            if (quad == 0) {
                af0[4] = *(const bf16x8*)(efpb + (size_t)nr0 * 8);
                af1[4] = *(const bf16x8*)(efpb + (size_t)nr1 * 8);
            }
        }

        // ---- epilogue: merged atomics over sorted dsts, both groups ----
        #pragma unroll
        for (int nt = 0; nt < 4; nt++) {
            int col = nt * 16 + l15;
            float bb = b2r[nt];
            float* ap = agg + col;
            {
                int dcur = d40.x;
                float v = oa0[nt][0] + bb;
                if (d40.y == dcur) v += oa0[nt][1] + bb;
                else { atomicAdd(ap + (size_t)dcur * 64, v); dcur = d40.y; v = oa0[nt][1] + bb; }
                if (d40.z == dcur) v += oa0[nt][2] + bb;
                else { atomicAdd(ap + (size_t)dcur * 64, v); dcur = d40.z; v = oa0[nt][2] + bb; }
                if (d40.w == dcur) v += oa0[nt][3] + bb;
                else { atomicAdd(ap + (size_t)dcur * 64, v); dcur = d40.w; v = oa0[nt][3] + bb; }
                atomicAdd(ap + (size_t)dcur * 64, v);
            }
            {
                int dcur = d41.x;
                float v = oa1[nt][0] + bb;
                if (d41.y == dcur) v += oa1[nt][1] + bb;
                else { atomicAdd(ap + (size_t)dcur * 64, v); dcur = d41.y; v = oa1[nt][1] + bb; }
                if (d41.z == dcur) v += oa1[nt][2] + bb;
                else { atomicAdd(ap + (size_t)dcur * 64, v); dcur = d41.z; v = oa1[nt][2] + bb; }
                if (d41.w == dcur) v += oa1[nt][3] + bb;
                else { atomicAdd(ap + (size_t)dcur * 64, v); dcur = d41.w; v = oa1[nt][3] + bb; }
                atomicAdd(ap + (size_t)dcur * 64, v);
            }
        }

        if (pn >= NPAIR) break;
        p = pn;
        d40 = d40n;
        d41 = d41n;
    }
}

// ---------------------------------------------------------------------------
// GRU (MFMA): 64 nodes/block, 16/wave. LAST=0: emits fp32 h + bf16 hb and
// ZEROES agg in place after reading (replaces the step-1 memset dispatch).
// LAST=1: fuses the readout MLP.
// ---------------------------------------------------------------------------
template<int LAST>
__global__ __launch_bounds__(256) void gru_kernel(
    float* __restrict__ agg, const float* __restrict__ h_in,
    float* __restrict__ h_out, bf16_t* __restrict__ hb_out,
    const bf16_t* __restrict__ Wxt, const bf16_t* __restrict__ Wht,
    const float* __restrict__ bg,
    const bf16_t* __restrict__ Wr1f, const float* __restrict__ br1,
    const float* __restrict__ Wr2, const float* __restrict__ br2,
    float* __restrict__ out)
{
    __shared__ __attribute__((aligned(16))) float  shd[64 * 68];    // 17408 B
    __shared__ __attribute__((aligned(16))) bf16_t hb2[4][16 * 72]; //  9216 B
    const int tid = threadIdx.x;
    const int n0  = blockIdx.x * 64;

    for (int idx = tid; idx < 64 * 16; idx += 256) {
        int i = idx >> 4, c = (idx & 15) * 4;
        int n = n0 + i; if (n >= NN) n = NN - 1;
        *(float4*)&shd[i * 68 + c] = *(const float4*)(h_in + (size_t)n * 64 + c);
    }
    __syncthreads();

    const int lane = tid & 63;
    const int wv   = tid >> 6;
    const int l15  = lane & 15;
    const int quad = lane >> 4;
    const int rowA = wv * 16 + l15;
    const bool rowOK = (n0 + rowA) < NN;
    int nA = n0 + rowA; if (!rowOK) nA = NN - 1;

    bf16x8 ax[2], ah[2];
    ax[0] = cvt8(agg + (size_t)nA * 64 + quad * 8);
    ax[1] = cvt8(agg + (size_t)nA * 64 + quad * 8 + 32);
    {
        const float* hp = shd + rowA * 68 + quad * 8;
        ah[0] = cvt8(hp);
        ah[1] = cvt8(hp + 32);
    }
    if (!LAST && rowOK) {
        // zero agg for the next edge step (this thread owns these 16 floats)
        float4 z = make_float4(0.f, 0.f, 0.f, 0.f);
        *(float4*)(agg + (size_t)nA * 64 + quad * 8)      = z;
        *(float4*)(agg + (size_t)nA * 64 + quad * 8 + 4)  = z;
        *(float4*)(agg + (size_t)nA * 64 + quad * 8 + 32) = z;
        *(float4*)(agg + (size_t)nA * 64 + quad * 8 + 36) = z;
    }

    floatx4 az[4], ar[4], axh[4], ahh[4];
    #pragma unroll
    for (int nt = 0; nt < 4; nt++) {
        az[nt].x=0.f; az[nt].y=0.f; az[nt].z=0.f; az[nt].w=0.f;
        ar[nt].x=0.f; ar[nt].y=0.f; ar[nt].z=0.f; ar[nt].w=0.f;
        axh[nt].x=0.f; axh[nt].y=0.f; axh[nt].z=0.f; axh[nt].w=0.f;
        ahh[nt].x=0.f; ahh[nt].y=0.f; ahh[nt].z=0.f; ahh[nt].w=0.f;
    }
    #pragma unroll
    for (int nt = 0; nt < 4; nt++) {
        const bf16_t* bx_z = Wxt + (nt * 16 + l15) * 64 + quad * 8;
        const bf16_t* bh_z = Wht + (nt * 16 + l15) * 64 + quad * 8;
        const bf16_t* bx_r = bx_z + 64 * 64;
        const bf16_t* bh_r = bh_z + 64 * 64;
        const bf16_t* bx_h = bx_z + 128 * 64;
        const bf16_t* bh_h = bh_z + 128 * 64;
        az[nt]  = mfma16(ax[0], *(const bf16x8*)bx_z,        az[nt]);
        az[nt]  = mfma16(ax[1], *(const bf16x8*)(bx_z + 32), az[nt]);
        az[nt]  = mfma16(ah[0], *(const bf16x8*)bh_z,        az[nt]);
        az[nt]  = mfma16(ah[1], *(const bf16x8*)(bh_z + 32), az[nt]);
        ar[nt]  = mfma16(ax[0], *(const bf16x8*)bx_r,        ar[nt]);
        ar[nt]  = mfma16(ax[1], *(const bf16x8*)(bx_r + 32), ar[nt]);
        ar[nt]  = mfma16(ah[0], *(const bf16x8*)bh_r,        ar[nt]);
        ar[nt]  = mfma16(ah[1], *(const bf16x8*)(bh_r + 32), ar[nt]);
        axh[nt] = mfma16(ax[0], *(const bf16x8*)bx_h,        axh[nt]);
        axh[nt] = mfma16(ax[1], *(const bf16x8*)(bx_h + 32), axh[nt]);
        ahh[nt] = mfma16(ah[0], *(const bf16x8*)bh_h,        ahh[nt]);
        ahh[nt] = mfma16(ah[1], *(const bf16x8*)(bh_h + 32), ahh[nt]);
    }

    #pragma unroll
    for (int nt = 0; nt < 4; nt++) {
        int j = nt * 16 + l15;
        float bz = bg[j], brr = bg[64 + j], bh = bg[128 + j];
        #pragma unroll
        for (int r = 0; r < 4; r++) {
            int lrow = wv * 16 + quad * 4 + r;
            int n = n0 + lrow;
            float z  = sigm_f(az[nt][r] + bz);
            float rr = sigm_f(ar[nt][r] + brr);
            float hc = tanh_f(axh[nt][r] + bh + rr * ahh[nt][r]);
            float hold = shd[lrow * 68 + j];
            float hnew = z * hold + (1.f - z) * hc;
            if (LAST) {
                hb2[wv][(quad * 4 + r) * 72 + j] = (bf16_t)hnew;
            } else if (n < NN) {
                h_out[(size_t)n * 64 + j]  = hnew;
                hb_out[(size_t)n * 64 + j] = (bf16_t)hnew;
            }
        }
    }

    if (LAST) {
        bf16x8 a0 = *(const bf16x8*)(hb2[wv] + l15 * 72 + quad * 8);
        bf16x8 a1 = *(const bf16x8*)(hb2[wv] + l15 * 72 + quad * 8 + 32);
        floatx4 accR[8];
        #pragma unroll
        for (int nt = 0; nt < 8; nt++) { accR[nt].x=0.f; accR[nt].y=0.f; accR[nt].z=0.f; accR[nt].w=0.f; }
        #pragma unroll
        for (int nt = 0; nt < 8; nt++) {
            bf16x8 b0 = *(const bf16x8*)(Wr1f + ((nt * 2 + 0) * 64 + lane) * 8);
            bf16x8 b1 = *(const bf16x8*)(Wr1f + ((nt * 2 + 1) * 64 + lane) * 8);
            accR[nt] = mfma16(a0, b0, accR[nt]);
            accR[nt] = mfma16(a1, b1, accR[nt]);
        }
        float br1r[8], wr2r[8];
        #pragma unroll
        for (int nt = 0; nt < 8; nt++) {
            br1r[nt] = br1[nt * 16 + l15];
            wr2r[nt] = Wr2[nt * 16 + l15];
        }
        float br2v = br2[0];
        #pragma unroll
        for (int r = 0; r < 4; r++) {
            float p = 0.f;
            #pragma unroll
            for (int nt = 0; nt < 8; nt++)
                p += fmaxf(accR[nt][r] + br1r[nt], 0.f) * wr2r[nt];
            p += __shfl_xor(p, 1, 64);
            p += __shfl_xor(p, 2, 64);
            p += __shfl_xor(p, 4, 64);
            p += __shfl_xor(p, 8, 64);
            if (l15 == 0) {
                int n = n0 + wv * 16 + quad * 4 + r;
                if (n < NN) out[n] = p + br2v;
            }
        }
    }
}

// ---------------------------------------------------------------------------
extern "C" void kernel_launch(void* const* d_in, const int* in_sizes, int n_in,
                              void* d_out, int out_size, void* d_ws, size_t ws_size,
                              hipStream_t stream)
{
    const float* nf  = (const float*)d_in[0];
    const float* ef  = (const float*)d_in[1];
    const int* esrc  = (const int*)d_in[2];
    const int* edst  = (const int*)d_in[3];
    const float* Wm1 = (const float*)d_in[4];
    const float* bm1 = (const float*)d_in[5];
    const float* Wm2 = (const float*)d_in[6];
    const float* bm2 = (const float*)d_in[7];
    const float* Wx  = (const float*)d_in[8];
    const float* Wh  = (const float*)d_in[9];
    const float* bg  = (const float*)d_in[10];
    const float* Wr1 = (const float*)d_in[11];
    const float* br1 = (const float*)d_in[12];
    const float* Wr2 = (const float*)d_in[13];
    const float* br2 = (const float*)d_in[14];

    char* ws = (char*)d_ws;
    float*  hbuf   = (float*)(ws);                   // 12,800,000
    bf16_t* hb     = (bf16_t*)(ws + 12800000);       // 6,400,000
    bf16_t* W1f    = (bf16_t*)(ws + 19200000);       // 40,960
    bf16_t* W2f    = (bf16_t*)(ws + 19240960);       // 16,384
    bf16_t* Wxt    = (bf16_t*)(ws + 19257344);       // 24,576
    bf16_t* Wht    = (bf16_t*)(ws + 19281920);       // 24,576
    bf16_t* Wr1f   = (bf16_t*)(ws + 19306496);       // 16,384
    int*    srcs   = (int*)(ws + 19322880);          // 1,600,000
    int*    dsts   = (int*)(ws + 20922880);          // 1,600,000
    bf16_t* efpb   = (bf16_t*)(ws + 22522880);       // 6,400,000
    int*    deg    = (int*)(ws + 28922880);          // 200,704
    float*  agg    = (float*)(ws + 29123584);        // 12,800,000 (adjacent to deg)
    int*    cursor = (int*)(ws + 41923584);          // 200,704
    int*    chunkS = (int*)(ws + 42124288);          // 1,024
    int*    chunkO = (int*)(ws + 42125312);          // 1,024

    prep_kernel<<<3365, 256, 0, stream>>>(nf, Wm1, Wm2, Wx, Wh, Wr1,
                                          hb, W1f, W2f, Wxt, Wht, Wr1f);

    // one memset covers deg + agg (adjacent)
    hipMemsetAsync(deg, 0, (size_t)NPAD * 4 + (size_t)NN * 64 * 4, stream);
    hist_kernel<<<(NE + 255) / 256, 256, 0, stream>>>(edst, deg);
    scanA_kernel<<<NCH, 256, 0, stream>>>(deg, chunkS);
    scanB_kernel<<<1, 256, 0, stream>>>(chunkS, chunkO);
    scanC_kernel<<<NCH, 256, 0, stream>>>(deg, chunkO, cursor);
    scatter_kernel<<<(NE + 255) / 256, 256, 0, stream>>>(esrc, edst, ef, cursor,
                                                         srcs, dsts, efpb);

    // step 0
    edge_kernel<<<1024, 256, 0, stream>>>(hb, efpb, srcs, dsts,
                                          W1f, W2f, bm1, bm2, agg);
    gru_kernel<0><<<(NN + 63) / 64, 256, 0, stream>>>(
        agg, nf, hbuf, hb, Wxt, Wht, bg, Wr1f, br1, Wr2, br2, (float*)d_out);
    // step 1 (agg zeroed by gru<0>)
    edge_kernel<<<1024, 256, 0, stream>>>(hb, efpb, srcs, dsts,
                                          W1f, W2f, bm1, bm2, agg);
    gru_kernel<1><<<(NN + 63) / 64, 256, 0, stream>>>(
        agg, hbuf, nullptr, nullptr, Wxt, Wht, bg, Wr1f, br1, Wr2, br2,
        (float*)d_out);
}